// Round 2
// baseline (260.875 us; speedup 1.0000x reference)
//
#include <hip/hip_runtime.h>
#include <hip/hip_cooperative_groups.h>
#include <math.h>

namespace cg = cooperative_groups;

#define N_TOT 8400
#define MASK_WORDS 132   // ceil(8400/64)
#define CAP 32           // max (word,bits) entries per row
#define RT 33            // rank tiles: ceil(8400/256)
#define NB 256           // blocks (1 per CU -> co-residency guaranteed)
#define NT 256           // threads per block (4 waves)

typedef unsigned long long u64;

// monotone-increasing float->u32 mapping
__device__ __forceinline__ unsigned mono_u32(float f) {
    unsigned u = __float_as_uint(f);
    return (u & 0x80000000u) ? ~u : (u | 0x80000000u);
}

// workspace layout (byte offsets into d_ws)
#define WS_LOGIT   0
#define WS_SIG     33600
#define WS_BOX     67200
#define WS_KPS     201600
#define WS_RANK    537600
#define WS_SLOGIT  571200
#define WS_SSIG    604800
#define WS_SBOX    638400
#define WS_SKPS    772800
#define WS_KEEP    1108800
#define WS_VALIDW  1110144
#define WS_ROWFLAG 1111296
#define WS_CNT     1112448
#define WS_KEY     1146368
#define WS_ENT     1213568

// ================= fused single-dispatch pipeline =================
// P0 decode -> P1 rank -> P2 scatter -> P3 pairs -> P4 nms -> P5 output,
// separated by cooperative grid syncs instead of kernel launches.
__global__ __launch_bounds__(NT) void fused_kernel(
        const float* __restrict__ score0, const float* __restrict__ bbox0, const float* __restrict__ kps0,
        const float* __restrict__ score1, const float* __restrict__ bbox1, const float* __restrict__ kps1,
        const float* __restrict__ score2, const float* __restrict__ bbox2, const float* __restrict__ kps2,
        char* __restrict__ ws, float* __restrict__ out) {
    cg::grid_group grid = cg::this_grid();
    const int tid = threadIdx.x;
    const int bid = blockIdx.x;
    const int gtid = bid * NT + tid;

    float* logit   = (float*)(ws + WS_LOGIT);
    float* sig     = (float*)(ws + WS_SIG);
    float* box     = (float*)(ws + WS_BOX);
    float* kps     = (float*)(ws + WS_KPS);
    int*   rank    = (int*)  (ws + WS_RANK);
    float* s_logit = (float*)(ws + WS_SLOGIT);
    float* s_sig   = (float*)(ws + WS_SSIG);
    float* s_box   = (float*)(ws + WS_SBOX);
    float* s_kps   = (float*)(ws + WS_SKPS);
    u64*   keep_words = (u64*)(ws + WS_KEEP);
    u64*   validw     = (u64*)(ws + WS_VALIDW);
    u64*   rowflag    = (u64*)(ws + WS_ROWFLAG);
    unsigned int* cnt = (unsigned int*)(ws + WS_CNT);
    u64*   key        = (u64*)(ws + WS_KEY);
    ulonglong2* ent   = (ulonglong2*)(ws + WS_ENT);

    __shared__ u64 tileK[256];            // P1
    __shared__ float4 cboxS[4][64];       // P3 (per wave)
    __shared__ float  careaS[4][64];      // P3 (per wave)
    __shared__ u64 rem_lds[MASK_WORDS];   // P4
    __shared__ unsigned short wlist[MASK_WORDS];  // P4

    // ---------------- P0: decode + sort keys + zero-init state ----------------
    if (gtid < N_TOT) {
        int i = gtid;
        if (i < MASK_WORDS) { validw[i] = 0ull; rowflag[i] = 0ull; }
        rank[i] = 0;
        cnt[i] = 0u;
        const float *sc, *bb, *kp;
        int m, F; float s;
        if (i < 6400)      { sc = score0; bb = bbox0; kp = kps0; m = i;        F = 80; s = 8.f;  }
        else if (i < 8000) { sc = score1; bb = bbox1; kp = kps1; m = i - 6400; F = 40; s = 16.f; }
        else               { sc = score2; bb = bbox2; kp = kps2; m = i - 8000; F = 20; s = 32.f; }
        float px = (float)(m % F) * s;
        float py = (float)(m / F) * s;
        float lg = sc[m];
        logit[i] = lg;
        sig[i] = 1.0f / (1.0f + expf(-lg));
        // descending-logit order with ascending-index tie-break, one ascending u64 key
        key[i] = ((u64)(~mono_u32(lg)) << 14) | (u64)i;
        float d0 = bb[m*4+0]*s, d1 = bb[m*4+1]*s, d2 = bb[m*4+2]*s, d3 = bb[m*4+3]*s;
        box[i*4+0] = px - d0;
        box[i*4+1] = py - d1;
        box[i*4+2] = px + d2;
        box[i*4+3] = py + d3;
        #pragma unroll
        for (int c = 0; c < 5; ++c) {
            kps[i*10 + 2*c]   = px + kp[m*10 + 2*c]   * s;
            kps[i*10 + 2*c+1] = py + kp[m*10 + 2*c+1] * s;
        }
    }
    grid.sync();

    // ---------------- P1: tiled rank = #{j : key[j] < key[i]} ----------------
    for (int t = bid; t < RT * RT; t += NB) {
        int it = t / RT, jt = t - it * RT;
        __syncthreads();                       // previous task done reading tileK
        int j = jt * 256 + tid;
        tileK[tid] = (j < N_TOT) ? key[j] : ~0ull;   // OOB sorts last
        __syncthreads();
        int i = it * 256 + tid;
        if (i < N_TOT) {
            u64 ki = key[i];
            int rk = 0;
            #pragma unroll 8
            for (int k = 0; k < 256; ++k) rk += (tileK[k] < ki) ? 1 : 0;
            if (rk) atomicAdd(&rank[i], rk);
        }
    }
    grid.sync();

    // ---------------- P2: scatter into sorted order + valid bits ----------------
    if (gtid < N_TOT) {
        int i = gtid;
        int r = rank[i];
        float lg = logit[i];
        s_logit[r] = lg;
        s_sig[r] = sig[i];
        #pragma unroll
        for (int c = 0; c < 4; ++c)  s_box[r*4+c] = box[i*4+c];
        #pragma unroll
        for (int c = 0; c < 10; ++c) s_kps[r*10+c] = kps[i*10+c];
        if (lg > 0.f) atomicOr(&validw[r >> 6], 1ull << (r & 63));
    }
    grid.sync();

    // ---------------- P3: sparse successor-overlap pairs (wave-task loop) ----------------
    {
        const int wv = tid >> 6, lane = tid & 63;
        const int gw = bid * 4 + wv;           // 0..1023
        for (int t = gw; t < 132 * 67; t += NB * 4) {
            int x = t % 132, y = t / 132;
            int rb, cw;
            bool skip = false;
            if (x + y < MASK_WORDS) { rb = x; cw = x + y; }
            else if (y == MASK_WORDS / 2) skip = true;   // wrapped y=66 duplicates direct
            else { rb = x + y - MASK_WORDS; cw = x; }
            if (skip) continue;

            int j = cw * 64 + lane;
            float4 cb = make_float4(0.f, 0.f, 0.f, 0.f);
            float lgj = -1.f;
            if (j < N_TOT) {
                cb = ((const float4*)s_box)[j];
                lgj = s_logit[j];
            }
            cboxS[wv][lane] = cb;              // wave-local LDS: in-order DS, no barrier
            careaS[wv][lane] = (cb.z - cb.x) * (cb.w - cb.y);
            u64 cvalid = __ballot(j < N_TOT && lgj > 0.f);
            if (cvalid == 0ull) continue;      // sorted => no valid columns at/after here

            int r = rb * 64 + lane;
            float lgr = (r < N_TOT) ? s_logit[r] : -1.f;
            if (__ballot(lgr > 0.f) == 0ull) continue;

            u64 bits = 0ull;
            if (lgr > 0.f) {
                float4 rb4 = ((const float4*)s_box)[r];
                float rarea = (rb4.z - rb4.x) * (rb4.w - rb4.y);
                #pragma unroll 4
                for (int k = 0; k < 64; ++k) {
                    float4 c4 = cboxS[wv][k];
                    float ltx = fmaxf(rb4.x, c4.x);
                    float lty = fmaxf(rb4.y, c4.y);
                    float rbx = fminf(rb4.z, c4.z);
                    float rby = fminf(rb4.w, c4.w);
                    float w = fmaxf(rbx - ltx, 0.f);
                    float h = fmaxf(rby - lty, 0.f);
                    float inter = w * h;
                    float iou = inter / (rarea + careaS[wv][k] - inter + 1e-9f);
                    bits |= (iou > 0.4f) ? (1ull << k) : 0ull;
                }
                u64 m = cvalid;
                if (cw == rb) m &= (lane == 63) ? 0ull : (~0ull << (lane + 1));
                bits &= m;
            }
            if (bits) {
                unsigned idx = atomicAdd(&cnt[r], 1u);
                if (idx < CAP) {
                    ulonglong2 e; e.x = bits; e.y = (u64)cw;
                    ent[(size_t)r * CAP + idx] = e;
                }
                atomicOr(&rowflag[r >> 6], 1ull << (r & 63));
            }
        }
    }
    grid.sync();

    // ---------------- P4: word-serial greedy resolve (block 0, wave 0) ----------------
    if (bid == 0 && tid < 64) {
        int lane = tid;
        u64 rf[3], vw[3];
        #pragma unroll
        for (int s = 0; s < 3; ++s) {
            int w = s * 64 + lane;
            rf[s] = (w < MASK_WORDS) ? rowflag[w] : 0ull;
            vw[s] = (w < MASK_WORDS) ? validw[w] : 0ull;
            if (w < MASK_WORDS) rem_lds[w] = 0ull;
        }

        // sorted list of words containing >=1 edge-row
        int base = 0;
        #pragma unroll
        for (int s = 0; s < 3; ++s) {
            bool nz = rf[s] != 0ull;
            u64 bal = __ballot(nz);
            int pos = __popcll(bal & ((1ull << lane) - 1ull));
            if (nz) wlist[base + pos] = (unsigned short)(s * 64 + lane);
            base += (int)__popcll(bal);
        }
        int n_w = base;

        auto LOADW = [&](int t, int &wd, unsigned &c, ulonglong2 &e0, ulonglong2 &e1, u64 &lb) {
            wd = 0; c = 0u; e0.x = 0ull; e0.y = 0ull; e1.x = 0ull; e1.y = 0ull; lb = 0ull;
            if (t < n_w) {
                wd = (int)wlist[t];
                int row = wd * 64 + lane;
                if (row < N_TOT) {
                    c = cnt[row];
                    if (c > 0u) { e0 = ent[(size_t)row * CAP];     if ((int)e0.y == wd) lb |= e0.x; }
                    if (c > 1u) { e1 = ent[(size_t)row * CAP + 1]; if ((int)e1.y == wd) lb |= e1.x; }
                    if (c > 2u) {
                        unsigned cm = min(c, (unsigned)CAP);
                        for (unsigned e = 2; e < cm; ++e) {
                            ulonglong2 g = ent[(size_t)row * CAP + e];
                            if ((int)g.y == wd) lb |= g.x;
                        }
                    }
                }
            }
        };

        int wA, wB; unsigned cA, cB; ulonglong2 eA0, eA1, eB0, eB1; u64 lbA, lbB;
        LOADW(0, wA, cA, eA0, eA1, lbA);
        LOADW(1, wB, cB, eB0, eB1, lbB);

        for (int t = 0; t < n_w; ++t) {
            int wC; unsigned cC; ulonglong2 eC0, eC1; u64 lbC;
            LOADW(t + 2, wC, cC, eC0, eC1, lbC);       // prefetch 2 ahead

            u64 remw = rem_lds[wA];                    // single wave: DS in-order
            u64 cand = __ballot(cA > 0u) & ~remw;
            if (cand) {
                u64 kept;
                u64 localmask = __ballot(lbA != 0ull) & cand;
                if (localmask == 0ull) {
                    kept = cand;                       // common: no intra-word edges
                } else {
                    kept = 0ull;
                    u64 remw_new = remw;
                    u64 pend = cand;
                    while (pend) {
                        int b = __builtin_ctzll(pend);
                        pend &= pend - 1ull;
                        if (!((remw_new >> b) & 1ull)) {
                            kept |= 1ull << b;
                            unsigned lo = (unsigned)__builtin_amdgcn_readlane((int)(unsigned)lbA, b);
                            unsigned hi = (unsigned)__builtin_amdgcn_readlane((int)(unsigned)(lbA >> 32), b);
                            remw_new |= ((u64)hi << 32) | (u64)lo;
                            pend &= ~remw_new;
                        }
                    }
                    if (lane == 0) rem_lds[wA] = remw_new;
                }
                if ((kept >> lane) & 1ull) {           // parallel far-edge application
                    if (cA > 0u) { int yw = (int)eA0.y; if (yw != wA) atomicOr(&rem_lds[yw], eA0.x); }
                    if (cA > 1u) { int yw = (int)eA1.y; if (yw != wA) atomicOr(&rem_lds[yw], eA1.x); }
                    if (cA > 2u) {
                        unsigned cm = min(cA, (unsigned)CAP);
                        int row = wA * 64 + lane;
                        for (unsigned e = 2; e < cm; ++e) {
                            ulonglong2 g = ent[(size_t)row * CAP + e];
                            int yw = (int)g.y;
                            if (yw != wA) atomicOr(&rem_lds[yw], g.x);
                        }
                    }
                }
            }
            wA = wB; cA = cB; eA0 = eB0; eA1 = eB1; lbA = lbB;
            wB = wC; cB = cC; eB0 = eC0; eB1 = eC1; lbB = lbC;
        }

        #pragma unroll
        for (int s = 0; s < 3; ++s) {
            int w = s * 64 + lane;
            if (w < MASK_WORDS) keep_words[w] = vw[s] & ~rem_lds[w];
        }
    }
    grid.sync();

    // ---------------- P5: write outputs ----------------
    if (gtid < N_TOT) {
        int r = gtid;
        float m = ((keep_words[r >> 6] >> (r & 63)) & 1ull) ? 1.0f : 0.0f;
        float* ob = out;                   // 8400*4
        float* os = out + 33600;           // 8400
        float* okp = out + 42000;          // 8400*10
        float* om = out + 126000;          // 8400
        #pragma unroll
        for (int c = 0; c < 4; ++c)  ob[r*4+c] = s_box[r*4+c] * m;
        os[r] = s_sig[r] * m;
        #pragma unroll
        for (int c = 0; c < 10; ++c) okp[r*10+c] = s_kps[r*10+c] * m;
        om[r] = m;
    }
}

// ================= fallback path (6 kernels), used only if cooperative launch errors =================
__global__ void decode_kernel(const float* __restrict__ score0, const float* __restrict__ bbox0, const float* __restrict__ kps0,
                              const float* __restrict__ score1, const float* __restrict__ bbox1, const float* __restrict__ kps1,
                              const float* __restrict__ score2, const float* __restrict__ bbox2, const float* __restrict__ kps2,
                              float* __restrict__ logit, float* __restrict__ sig,
                              float* __restrict__ box, float* __restrict__ kps,
                              u64* __restrict__ key, int* __restrict__ rank,
                              unsigned int* __restrict__ cnt,
                              u64* __restrict__ validw, u64* __restrict__ rowflag) {
    int i = blockIdx.x * blockDim.x + threadIdx.x;
    if (i >= N_TOT) return;
    if (i < MASK_WORDS) { validw[i] = 0ull; rowflag[i] = 0ull; }
    rank[i] = 0;
    cnt[i] = 0u;
    const float *sc, *bb, *kp;
    int m, F; float s;
    if (i < 6400)      { sc = score0; bb = bbox0; kp = kps0; m = i;        F = 80; s = 8.f;  }
    else if (i < 8000) { sc = score1; bb = bbox1; kp = kps1; m = i - 6400; F = 40; s = 16.f; }
    else               { sc = score2; bb = bbox2; kp = kps2; m = i - 8000; F = 20; s = 32.f; }
    float px = (float)(m % F) * s;
    float py = (float)(m / F) * s;
    float lg = sc[m];
    logit[i] = lg;
    sig[i] = 1.0f / (1.0f + expf(-lg));
    key[i] = ((u64)(~mono_u32(lg)) << 14) | (u64)i;
    float d0 = bb[m*4+0]*s, d1 = bb[m*4+1]*s, d2 = bb[m*4+2]*s, d3 = bb[m*4+3]*s;
    box[i*4+0] = px - d0;
    box[i*4+1] = py - d1;
    box[i*4+2] = px + d2;
    box[i*4+3] = py + d3;
    #pragma unroll
    for (int c = 0; c < 5; ++c) {
        kps[i*10 + 2*c]   = px + kp[m*10 + 2*c]   * s;
        kps[i*10 + 2*c+1] = py + kp[m*10 + 2*c+1] * s;
    }
}

__global__ __launch_bounds__(256) void rank_kernel(const u64* __restrict__ key, int* __restrict__ rank) {
    __shared__ u64 tile[256];
    int i = blockIdx.x * 256 + threadIdx.x;
    int t0 = blockIdx.y * 256;
    u64 ki = (i < N_TOT) ? key[i] : 0ull;
    int j = t0 + threadIdx.x;
    tile[threadIdx.x] = (j < N_TOT) ? key[j] : ~0ull;
    __syncthreads();
    if (i >= N_TOT) return;
    int rk = 0;
    #pragma unroll 8
    for (int k = 0; k < 256; ++k) rk += (tile[k] < ki) ? 1 : 0;
    if (rk) atomicAdd(&rank[i], rk);
}

__global__ void scatter_kernel(const int* __restrict__ rank,
                               const float* __restrict__ logit, const float* __restrict__ sig,
                               const float* __restrict__ box, const float* __restrict__ kps,
                               float* __restrict__ s_logit, float* __restrict__ s_sig,
                               float* __restrict__ s_box, float* __restrict__ s_kps,
                               u64* __restrict__ validw) {
    int i = blockIdx.x * blockDim.x + threadIdx.x;
    if (i >= N_TOT) return;
    int r = rank[i];
    float lg = logit[i];
    s_logit[r] = lg;
    s_sig[r] = sig[i];
    #pragma unroll
    for (int c = 0; c < 4; ++c)  s_box[r*4+c] = box[i*4+c];
    #pragma unroll
    for (int c = 0; c < 10; ++c) s_kps[r*10+c] = kps[i*10+c];
    if (lg > 0.f) atomicOr(&validw[r >> 6], 1ull << (r & 63));
}

__global__ __launch_bounds__(64) void pairs_kernel(const float* __restrict__ s_logit,
                                                   const float* __restrict__ s_box,
                                                   unsigned int* __restrict__ cnt,
                                                   ulonglong2* __restrict__ ent,
                                                   u64* __restrict__ rowflag) {
    int x = blockIdx.x, y = blockIdx.y;
    int rb, cw;
    if (x + y < MASK_WORDS) { rb = x; cw = x + y; }
    else {
        if (y == MASK_WORDS / 2) return;
        rb = x + y - MASK_WORDS; cw = x;
    }
    int tid = threadIdx.x;
    __shared__ float4 cbox[64];
    __shared__ float  carea[64];
    int j = cw * 64 + tid;
    float4 cb = make_float4(0.f, 0.f, 0.f, 0.f);
    float lgj = -1.f;
    if (j < N_TOT) { cb = ((const float4*)s_box)[j]; lgj = s_logit[j]; }
    cbox[tid] = cb;
    carea[tid] = (cb.z - cb.x) * (cb.w - cb.y);
    u64 cvalid = __ballot(j < N_TOT && lgj > 0.f);
    __syncthreads();
    if (cvalid == 0ull) return;
    int r = rb * 64 + tid;
    float lgr = (r < N_TOT) ? s_logit[r] : -1.f;
    if (__ballot(lgr > 0.f) == 0ull) return;
    u64 bits = 0ull;
    if (lgr > 0.f) {
        float4 rb4 = ((const float4*)s_box)[r];
        float rarea = (rb4.z - rb4.x) * (rb4.w - rb4.y);
        #pragma unroll 4
        for (int k = 0; k < 64; ++k) {
            float4 c4 = cbox[k];
            float ltx = fmaxf(rb4.x, c4.x);
            float lty = fmaxf(rb4.y, c4.y);
            float rbx = fminf(rb4.z, c4.z);
            float rby = fminf(rb4.w, c4.w);
            float w = fmaxf(rbx - ltx, 0.f);
            float h = fmaxf(rby - lty, 0.f);
            float inter = w * h;
            float iou = inter / (rarea + carea[k] - inter + 1e-9f);
            bits |= (iou > 0.4f) ? (1ull << k) : 0ull;
        }
        u64 m = cvalid;
        if (cw == rb) m &= (tid == 63) ? 0ull : (~0ull << (tid + 1));
        bits &= m;
    }
    if (bits) {
        unsigned idx = atomicAdd(&cnt[r], 1u);
        if (idx < CAP) {
            ulonglong2 e; e.x = bits; e.y = (u64)cw;
            ent[(size_t)r * CAP + idx] = e;
        }
        atomicOr(&rowflag[r >> 6], 1ull << (r & 63));
    }
}

__global__ __launch_bounds__(64) void nms_kernel(const u64* __restrict__ rowflag_g,
                                                 const u64* __restrict__ validw_g,
                                                 const unsigned int* __restrict__ cnt_g,
                                                 const ulonglong2* __restrict__ ent_g,
                                                 u64* __restrict__ keep_words) {
    __shared__ u64 rem_lds[MASK_WORDS];
    __shared__ unsigned short wlist[MASK_WORDS];
    int lane = threadIdx.x;
    u64 rf[3], vw[3];
    #pragma unroll
    for (int s = 0; s < 3; ++s) {
        int w = s * 64 + lane;
        rf[s] = (w < MASK_WORDS) ? rowflag_g[w] : 0ull;
        vw[s] = (w < MASK_WORDS) ? validw_g[w] : 0ull;
        if (w < MASK_WORDS) rem_lds[w] = 0ull;
    }
    int base = 0;
    #pragma unroll
    for (int s = 0; s < 3; ++s) {
        bool nz = rf[s] != 0ull;
        u64 bal = __ballot(nz);
        int pos = __popcll(bal & ((1ull << lane) - 1ull));
        if (nz) wlist[base + pos] = (unsigned short)(s * 64 + lane);
        base += (int)__popcll(bal);
    }
    int n_w = base;
    __syncthreads();
    auto LOADW = [&](int t, int &wd, unsigned &c, ulonglong2 &e0, ulonglong2 &e1, u64 &lb) {
        wd = 0; c = 0u; e0.x = 0ull; e0.y = 0ull; e1.x = 0ull; e1.y = 0ull; lb = 0ull;
        if (t < n_w) {
            wd = (int)wlist[t];
            int row = wd * 64 + lane;
            if (row < N_TOT) {
                c = cnt_g[row];
                if (c > 0u) { e0 = ent_g[(size_t)row * CAP];     if ((int)e0.y == wd) lb |= e0.x; }
                if (c > 1u) { e1 = ent_g[(size_t)row * CAP + 1]; if ((int)e1.y == wd) lb |= e1.x; }
                if (c > 2u) {
                    unsigned cm = min(c, (unsigned)CAP);
                    for (unsigned e = 2; e < cm; ++e) {
                        ulonglong2 g = ent_g[(size_t)row * CAP + e];
                        if ((int)g.y == wd) lb |= g.x;
                    }
                }
            }
        }
    };
    int wA, wB; unsigned cA, cB; ulonglong2 eA0, eA1, eB0, eB1; u64 lbA, lbB;
    LOADW(0, wA, cA, eA0, eA1, lbA);
    LOADW(1, wB, cB, eB0, eB1, lbB);
    for (int t = 0; t < n_w; ++t) {
        int wC; unsigned cC; ulonglong2 eC0, eC1; u64 lbC;
        LOADW(t + 2, wC, cC, eC0, eC1, lbC);
        __syncthreads();
        u64 remw = rem_lds[wA];
        u64 cand = __ballot(cA > 0u) & ~remw;
        if (cand) {
            u64 kept;
            u64 localmask = __ballot(lbA != 0ull) & cand;
            if (localmask == 0ull) kept = cand;
            else {
                kept = 0ull;
                u64 remw_new = remw;
                u64 pend = cand;
                while (pend) {
                    int b = __builtin_ctzll(pend);
                    pend &= pend - 1ull;
                    if (!((remw_new >> b) & 1ull)) {
                        kept |= 1ull << b;
                        unsigned lo = (unsigned)__builtin_amdgcn_readlane((int)(unsigned)lbA, b);
                        unsigned hi = (unsigned)__builtin_amdgcn_readlane((int)(unsigned)(lbA >> 32), b);
                        remw_new |= ((u64)hi << 32) | (u64)lo;
                        pend &= ~remw_new;
                    }
                }
                if (lane == 0) rem_lds[wA] = remw_new;
            }
            if ((kept >> lane) & 1ull) {
                if (cA > 0u) { int yw = (int)eA0.y; if (yw != wA) atomicOr(&rem_lds[yw], eA0.x); }
                if (cA > 1u) { int yw = (int)eA1.y; if (yw != wA) atomicOr(&rem_lds[yw], eA1.x); }
                if (cA > 2u) {
                    unsigned cm = min(cA, (unsigned)CAP);
                    int row = wA * 64 + lane;
                    for (unsigned e = 2; e < cm; ++e) {
                        ulonglong2 g = ent_g[(size_t)row * CAP + e];
                        int yw = (int)g.y;
                        if (yw != wA) atomicOr(&rem_lds[yw], g.x);
                    }
                }
            }
        }
        wA = wB; cA = cB; eA0 = eB0; eA1 = eB1; lbA = lbB;
        wB = wC; cB = cC; eB0 = eC0; eB1 = eC1; lbB = lbC;
    }
    __syncthreads();
    #pragma unroll
    for (int s = 0; s < 3; ++s) {
        int w = s * 64 + lane;
        if (w < MASK_WORDS) keep_words[w] = vw[s] & ~rem_lds[w];
    }
}

__global__ void output_kernel(const float* __restrict__ s_sig, const float* __restrict__ s_box,
                              const float* __restrict__ s_kps,
                              const u64* __restrict__ keep_words,
                              float* __restrict__ out) {
    int r = blockIdx.x * blockDim.x + threadIdx.x;
    if (r >= N_TOT) return;
    float m = ((keep_words[r >> 6] >> (r & 63)) & 1ull) ? 1.0f : 0.0f;
    float* ob = out;
    float* os = out + 33600;
    float* okp = out + 42000;
    float* om = out + 126000;
    #pragma unroll
    for (int c = 0; c < 4; ++c)  ob[r*4+c] = s_box[r*4+c] * m;
    os[r] = s_sig[r] * m;
    #pragma unroll
    for (int c = 0; c < 10; ++c) okp[r*10+c] = s_kps[r*10+c] * m;
    om[r] = m;
}

extern "C" void kernel_launch(void* const* d_in, const int* in_sizes, int n_in,
                              void* d_out, int out_size, void* d_ws, size_t ws_size,
                              hipStream_t stream) {
    const float *score0, *bbox0, *kps0, *score1, *bbox1, *kps1, *score2, *bbox2, *kps2;
    if (in_sizes[1] == 25600) {
        score0 = (const float*)d_in[0]; bbox0 = (const float*)d_in[1]; kps0 = (const float*)d_in[2];
        score1 = (const float*)d_in[3]; bbox1 = (const float*)d_in[4]; kps1 = (const float*)d_in[5];
        score2 = (const float*)d_in[6]; bbox2 = (const float*)d_in[7]; kps2 = (const float*)d_in[8];
    } else {
        score0 = (const float*)d_in[0]; score1 = (const float*)d_in[1]; score2 = (const float*)d_in[2];
        bbox0  = (const float*)d_in[3]; bbox1  = (const float*)d_in[4]; bbox2  = (const float*)d_in[5];
        kps0   = (const float*)d_in[6]; kps1   = (const float*)d_in[7]; kps2   = (const float*)d_in[8];
    }

    char* ws = (char*)d_ws;
    float* out = (float*)d_out;

    // ---- single cooperative dispatch ----
    void* args[] = {
        (void*)&score0, (void*)&bbox0, (void*)&kps0,
        (void*)&score1, (void*)&bbox1, (void*)&kps1,
        (void*)&score2, (void*)&bbox2, (void*)&kps2,
        (void*)&ws, (void*)&out
    };
    hipError_t err = hipLaunchCooperativeKernel(fused_kernel, dim3(NB), dim3(NT), args, 0u, stream);
    if (err == hipSuccess) return;

    // ---- fallback: proven 6-kernel pipeline ----
    float* logit   = (float*)(ws + WS_LOGIT);
    float* sig     = (float*)(ws + WS_SIG);
    float* box     = (float*)(ws + WS_BOX);
    float* kps     = (float*)(ws + WS_KPS);
    int*   rank    = (int*)  (ws + WS_RANK);
    float* s_logit = (float*)(ws + WS_SLOGIT);
    float* s_sig   = (float*)(ws + WS_SSIG);
    float* s_box   = (float*)(ws + WS_SBOX);
    float* s_kps   = (float*)(ws + WS_SKPS);
    u64*   keep_words = (u64*)(ws + WS_KEEP);
    u64*   validw     = (u64*)(ws + WS_VALIDW);
    u64*   rowflag    = (u64*)(ws + WS_ROWFLAG);
    unsigned int* cnt = (unsigned int*)(ws + WS_CNT);
    u64*   key        = (u64*)(ws + WS_KEY);
    ulonglong2*   ent = (ulonglong2*)(ws + WS_ENT);

    decode_kernel<<<(N_TOT + 255) / 256, 256, 0, stream>>>(
        score0, bbox0, kps0, score1, bbox1, kps1, score2, bbox2, kps2,
        logit, sig, box, kps, key, rank, cnt, validw, rowflag);
    rank_kernel<<<dim3(RT, RT), 256, 0, stream>>>(key, rank);
    scatter_kernel<<<33, 256, 0, stream>>>(rank, logit, sig, box, kps,
                                           s_logit, s_sig, s_box, s_kps, validw);
    pairs_kernel<<<dim3(MASK_WORDS, MASK_WORDS / 2 + 1), 64, 0, stream>>>(s_logit, s_box, cnt, ent, rowflag);
    nms_kernel<<<1, 64, 0, stream>>>(rowflag, validw, cnt, ent, keep_words);
    output_kernel<<<33, 256, 0, stream>>>(s_sig, s_box, s_kps, keep_words, out);
}

// Round 3
// 152.561 us; speedup vs baseline: 1.7100x; 1.7100x over previous
//
#include <hip/hip_runtime.h>
#include <math.h>

#define N_TOT 8400
#define MASK_WORDS 132   // ceil(8400/64)
#define CAP 32           // max (word,bits) entries per row
#define NBB 256          // kernel B blocks
#define NBA 525          // kernel A blocks: 8400 elems * 16 threads / 256

typedef unsigned long long u64;

// monotone-increasing float->u32 mapping
__device__ __forceinline__ unsigned mono_u32(float f) {
    unsigned u = __float_as_uint(f);
    return (u & 0x80000000u) ? ~u : (u | 0x80000000u);
}

// workspace layout (byte offsets)
#define WS_SLOGIT  0         // 8400*4 = 33600
#define WS_SBOX    33600     // 8400*16 = 134400 (16B aligned)
#define WS_CNT     168000    // 8400*4 = 33600
#define WS_ROWFLAG 201600    // 132*8 = 1056
#define WS_DONE    202656    // 4 (+pad)
#define WS_ENT     202672    // 8400*32*16 = 4300800 (16B aligned)

// ================= Kernel A: decode + rank + sorted scatter =================
// Rank needs all 8400 keys, but keys depend only on the 33.6KB score inputs ->
// every block redundantly builds the full key set in its own LDS (67.2KB) and
// ranks its 16 owned elements with 16 threads each (stride-16 scan, shfl reduce).
// Leaders then decode and write straight to sorted positions AND to out
// (unmasked; kernel B's last block later zeroes suppressed rows + writes mask).
__global__ __launch_bounds__(256) void decode_rank_kernel(
        const float* __restrict__ score0, const float* __restrict__ bbox0, const float* __restrict__ kps0,
        const float* __restrict__ score1, const float* __restrict__ bbox1, const float* __restrict__ kps1,
        const float* __restrict__ score2, const float* __restrict__ bbox2, const float* __restrict__ kps2,
        float* __restrict__ s_logit, float* __restrict__ s_box,
        unsigned* __restrict__ cnt, u64* __restrict__ rowflag, unsigned* __restrict__ done_ctr,
        float* __restrict__ out) {
    __shared__ u64 keyL[N_TOT];
    const int tid = threadIdx.x;
    const int gtid = blockIdx.x * 256 + tid;

    // zero state for kernel B (kernel boundary guarantees visibility/order)
    if (gtid < N_TOT) cnt[gtid] = 0u;
    if (gtid < MASK_WORDS) rowflag[gtid] = 0ull;
    if (gtid == 0) *done_ctr = 0u;

    // build all 8400 keys in LDS (33 coalesced rounds; scores are L1/L2-hot)
    for (int j = tid; j < N_TOT; j += 256) {
        const float* sc; int m;
        if (j < 6400)      { sc = score0; m = j; }
        else if (j < 8000) { sc = score1; m = j - 6400; }
        else               { sc = score2; m = j - 8000; }
        float lg = sc[m];
        // descending-logit order, ascending-index tie-break, one ascending u64 key
        keyL[j] = ((u64)(~mono_u32(lg)) << 14) | (u64)j;
    }
    __syncthreads();

    const int i = gtid >> 4;      // owned element (exactly 8400 groups)
    const int sub = tid & 15;     // 16 threads per element
    u64 ki = keyL[i];
    int rk = 0;
    // stride-16 partition: per step, 16 distinct b64 addrs spread across banks,
    // 4 lane-groups broadcast the same address -> conflict-free
    #pragma unroll 7
    for (int k = 0; k < N_TOT / 16; ++k) {
        rk += (keyL[sub + (k << 4)] < ki) ? 1 : 0;
    }
    rk += __shfl_xor(rk, 1);
    rk += __shfl_xor(rk, 2);
    rk += __shfl_xor(rk, 4);
    rk += __shfl_xor(rk, 8);

    if (sub == 0) {
        int r = rk;   // sorted position of element i
        const float *sc, *bb, *kp; int m, F; float s;
        if (i < 6400)      { sc=score0; bb=bbox0; kp=kps0; m=i;       F=80; s=8.f;  }
        else if (i < 8000) { sc=score1; bb=bbox1; kp=kps1; m=i-6400;  F=40; s=16.f; }
        else               { sc=score2; bb=bbox2; kp=kps2; m=i-8000;  F=20; s=32.f; }
        float px = (float)(m % F) * s;
        float py = (float)(m / F) * s;
        float lg = sc[m];
        s_logit[r] = lg;
        float d0=bb[m*4+0]*s, d1=bb[m*4+1]*s, d2=bb[m*4+2]*s, d3=bb[m*4+3]*s;
        float x1 = px - d0, y1 = py - d1, x2 = px + d2, y2 = py + d3;
        ((float4*)s_box)[r] = make_float4(x1, y1, x2, y2);
        float* ob  = out;            // 8400*4
        float* os  = out + 33600;    // 8400
        float* okp = out + 42000;    // 8400*10
        ob[r*4+0]=x1; ob[r*4+1]=y1; ob[r*4+2]=x2; ob[r*4+3]=y2;
        os[r] = 1.0f / (1.0f + expf(-lg));
        #pragma unroll
        for (int c = 0; c < 5; ++c) {
            okp[r*10 + 2*c]   = px + kp[m*10 + 2*c]   * s;
            okp[r*10 + 2*c+1] = py + kp[m*10 + 2*c+1] * s;
        }
    }
}

// ================= Kernel B: pairs + nms + output finalize =================
// 256 blocks x 4 waves run the triangular pair tasks; last-finishing block
// (threadfence + completion counter) runs the word-serial greedy NMS on wave 0
// and then finalizes out: writes the mask channel and zeroes suppressed rows.
__global__ __launch_bounds__(256) void pairs_nms_kernel(
        const float* __restrict__ s_logit, const float* __restrict__ s_box,
        unsigned* __restrict__ cnt, ulonglong2* __restrict__ ent,
        u64* __restrict__ rowflag, unsigned* __restrict__ done_ctr,
        float* __restrict__ out) {
    __shared__ float4 cboxS[4][64];
    __shared__ float  careaS[4][64];
    __shared__ u64 vw_lds[MASK_WORDS];
    __shared__ u64 rem_lds[MASK_WORDS];
    __shared__ unsigned short wlist[MASK_WORDS];
    __shared__ int lastF;

    const int tid = threadIdx.x;
    const int wv = tid >> 6, lane = tid & 63;
    const int gw = blockIdx.x * 4 + wv;

    // ---- pairs: triangular wave-task loop ----
    for (int t = gw; t < 132 * 67; t += NBB * 4) {
        int x = t % 132, y = t / 132;
        int rb, cw;
        if (x + y < MASK_WORDS) { rb = x; cw = x + y; }
        else if (y == MASK_WORDS / 2) continue;      // wrapped y=66 duplicates direct
        else { rb = x + y - MASK_WORDS; cw = x; }

        int j = cw * 64 + lane;
        float4 cb = make_float4(0.f, 0.f, 0.f, 0.f);
        float lgj = -1.f;
        if (j < N_TOT) {
            cb = ((const float4*)s_box)[j];
            lgj = s_logit[j];
        }
        cboxS[wv][lane] = cb;              // wave-local LDS: in-order, no barrier
        careaS[wv][lane] = (cb.z - cb.x) * (cb.w - cb.y);
        u64 cvalid = __ballot(j < N_TOT && lgj > 0.f);
        if (cvalid == 0ull) continue;      // sorted => no valid columns here

        int r = rb * 64 + lane;
        float lgr = (r < N_TOT) ? s_logit[r] : -1.f;
        if (__ballot(lgr > 0.f) == 0ull) continue;

        u64 bits = 0ull;
        if (lgr > 0.f) {
            float4 rb4 = ((const float4*)s_box)[r];
            float rarea = (rb4.z - rb4.x) * (rb4.w - rb4.y);
            #pragma unroll 4
            for (int k = 0; k < 64; ++k) {
                float4 c4 = cboxS[wv][k];
                float ltx = fmaxf(rb4.x, c4.x);
                float lty = fmaxf(rb4.y, c4.y);
                float rbx = fminf(rb4.z, c4.z);
                float rby = fminf(rb4.w, c4.w);
                float w = fmaxf(rbx - ltx, 0.f);
                float h = fmaxf(rby - lty, 0.f);
                float inter = w * h;
                float iou = inter / (rarea + careaS[wv][k] - inter + 1e-9f);
                bits |= (iou > 0.4f) ? (1ull << k) : 0ull;
            }
            u64 m = cvalid;
            if (cw == rb) m &= (lane == 63) ? 0ull : (~0ull << (lane + 1));
            bits &= m;
        }
        if (bits) {
            unsigned idx = atomicAdd(&cnt[r], 1u);
            if (idx < CAP) {
                ulonglong2 e; e.x = bits; e.y = (u64)cw;
                ent[(size_t)r * CAP + idx] = e;
            }
            atomicOr(&rowflag[r >> 6], 1ull << (r & 63));
        }
    }

    // ---- completion counter: last block proceeds ----
    __threadfence();                       // release this block's ent stores
    __syncthreads();
    if (tid == 0) {
        unsigned p = atomicAdd(done_ctr, 1u);
        lastF = (p == NBB - 1u) ? 1 : 0;
    }
    __syncthreads();
    if (!lastF) return;
    __threadfence();                       // acquire: other blocks' stores visible

    // build validw from s_logit (each wave handles 33 words via ballots)
    for (int q = wv * 33; q < wv * 33 + 33; ++q) {
        int row = q * 64 + lane;
        float lgq = (row < N_TOT) ? s_logit[row] : -1.f;
        u64 b = __ballot(lgq > 0.f);
        if (lane == 0) vw_lds[q] = b;
    }
    for (int q = tid; q < MASK_WORDS; q += 256) rem_lds[q] = 0ull;
    __syncthreads();

    // ---- word-serial greedy NMS on wave 0 (proven structure) ----
    if (wv == 0) {
        u64 rf[3];
        #pragma unroll
        for (int s = 0; s < 3; ++s) {
            int w = s * 64 + lane;
            rf[s] = (w < MASK_WORDS) ? rowflag[w] : 0ull;
        }
        int base = 0;
        #pragma unroll
        for (int s = 0; s < 3; ++s) {
            bool nz = rf[s] != 0ull;
            u64 bal = __ballot(nz);
            int pos = __popcll(bal & ((1ull << lane) - 1ull));
            if (nz) wlist[base + pos] = (unsigned short)(s * 64 + lane);
            base += (int)__popcll(bal);
        }
        int n_w = base;

        auto LOADW = [&](int t, int &wd, unsigned &c, ulonglong2 &e0, ulonglong2 &e1, u64 &lb) {
            wd = 0; c = 0u; e0.x = 0ull; e0.y = 0ull; e1.x = 0ull; e1.y = 0ull; lb = 0ull;
            if (t < n_w) {
                wd = (int)wlist[t];
                int row = wd * 64 + lane;
                if (row < N_TOT) {
                    c = cnt[row];
                    if (c > 0u) { e0 = ent[(size_t)row * CAP];     if ((int)e0.y == wd) lb |= e0.x; }
                    if (c > 1u) { e1 = ent[(size_t)row * CAP + 1]; if ((int)e1.y == wd) lb |= e1.x; }
                    if (c > 2u) {
                        unsigned cm = min(c, (unsigned)CAP);
                        for (unsigned e = 2; e < cm; ++e) {
                            ulonglong2 g = ent[(size_t)row * CAP + e];
                            if ((int)g.y == wd) lb |= g.x;
                        }
                    }
                }
            }
        };

        int wA, wB; unsigned cA, cB; ulonglong2 eA0, eA1, eB0, eB1; u64 lbA, lbB;
        LOADW(0, wA, cA, eA0, eA1, lbA);
        LOADW(1, wB, cB, eB0, eB1, lbB);

        for (int t = 0; t < n_w; ++t) {
            int wC; unsigned cC; ulonglong2 eC0, eC1; u64 lbC;
            LOADW(t + 2, wC, cC, eC0, eC1, lbC);       // prefetch 2 ahead

            u64 remw = rem_lds[wA];                    // single wave: DS in-order
            u64 cand = __ballot(cA > 0u) & ~remw;
            if (cand) {
                u64 kept;
                u64 localmask = __ballot(lbA != 0ull) & cand;
                if (localmask == 0ull) {
                    kept = cand;                       // common: no intra-word edges
                } else {
                    kept = 0ull;
                    u64 remw_new = remw;
                    u64 pend = cand;
                    while (pend) {
                        int b = __builtin_ctzll(pend);
                        pend &= pend - 1ull;
                        if (!((remw_new >> b) & 1ull)) {
                            kept |= 1ull << b;
                            unsigned lo = (unsigned)__builtin_amdgcn_readlane((int)(unsigned)lbA, b);
                            unsigned hi = (unsigned)__builtin_amdgcn_readlane((int)(unsigned)(lbA >> 32), b);
                            remw_new |= ((u64)hi << 32) | (u64)lo;
                            pend &= ~remw_new;
                        }
                    }
                    if (lane == 0) rem_lds[wA] = remw_new;
                }
                if ((kept >> lane) & 1ull) {           // parallel far-edge application
                    if (cA > 0u) { int yw = (int)eA0.y; if (yw != wA) atomicOr(&rem_lds[yw], eA0.x); }
                    if (cA > 1u) { int yw = (int)eA1.y; if (yw != wA) atomicOr(&rem_lds[yw], eA1.x); }
                    if (cA > 2u) {
                        unsigned cm = min(cA, (unsigned)CAP);
                        int row = wA * 64 + lane;
                        for (unsigned e = 2; e < cm; ++e) {
                            ulonglong2 g = ent[(size_t)row * CAP + e];
                            int yw = (int)g.y;
                            if (yw != wA) atomicOr(&rem_lds[yw], g.x);
                        }
                    }
                }
            }
            wA = wB; cA = cB; eA0 = eB0; eA1 = eB1; lbA = lbB;
            wB = wC; cB = cC; eB0 = eC0; eB1 = eC1; lbB = lbC;
        }
    }
    __syncthreads();

    // ---- finalize out: mask channel for all rows, zero suppressed rows ----
    {
        float* ob  = out;            // 8400*4
        float* os  = out + 33600;    // 8400
        float* okp = out + 42000;    // 8400*10
        float* om  = out + 126000;   // 8400
        for (int r = tid; r < N_TOT; r += 256) {
            u64 kw = vw_lds[r >> 6] & ~rem_lds[r >> 6];
            bool keep = (kw >> (r & 63)) & 1ull;
            om[r] = keep ? 1.0f : 0.0f;
            if (!keep) {
                ((float4*)ob)[r] = make_float4(0.f, 0.f, 0.f, 0.f);
                os[r] = 0.f;
                #pragma unroll
                for (int c = 0; c < 10; ++c) okp[r*10 + c] = 0.f;
            }
        }
    }
}

extern "C" void kernel_launch(void* const* d_in, const int* in_sizes, int n_in,
                              void* d_out, int out_size, void* d_ws, size_t ws_size,
                              hipStream_t stream) {
    const float *score0, *bbox0, *kps0, *score1, *bbox1, *kps1, *score2, *bbox2, *kps2;
    if (in_sizes[1] == 25600) {
        score0 = (const float*)d_in[0]; bbox0 = (const float*)d_in[1]; kps0 = (const float*)d_in[2];
        score1 = (const float*)d_in[3]; bbox1 = (const float*)d_in[4]; kps1 = (const float*)d_in[5];
        score2 = (const float*)d_in[6]; bbox2 = (const float*)d_in[7]; kps2 = (const float*)d_in[8];
    } else {
        score0 = (const float*)d_in[0]; score1 = (const float*)d_in[1]; score2 = (const float*)d_in[2];
        bbox0  = (const float*)d_in[3]; bbox1  = (const float*)d_in[4]; bbox2  = (const float*)d_in[5];
        kps0   = (const float*)d_in[6]; kps1   = (const float*)d_in[7]; kps2   = (const float*)d_in[8];
    }

    char* ws = (char*)d_ws;
    float* s_logit      = (float*)(ws + WS_SLOGIT);
    float* s_box        = (float*)(ws + WS_SBOX);
    unsigned* cnt       = (unsigned*)(ws + WS_CNT);
    u64* rowflag        = (u64*)(ws + WS_ROWFLAG);
    unsigned* done_ctr  = (unsigned*)(ws + WS_DONE);
    ulonglong2* ent     = (ulonglong2*)(ws + WS_ENT);
    float* out = (float*)d_out;

    decode_rank_kernel<<<NBA, 256, 0, stream>>>(
        score0, bbox0, kps0, score1, bbox1, kps1, score2, bbox2, kps2,
        s_logit, s_box, cnt, rowflag, done_ctr, out);
    pairs_nms_kernel<<<NBB, 256, 0, stream>>>(
        s_logit, s_box, cnt, ent, rowflag, done_ctr, out);
}

// Round 4
// 147.978 us; speedup vs baseline: 1.7629x; 1.0310x over previous
//
#include <hip/hip_runtime.h>
#include <math.h>

#define N_TOT 8400
#define MASK_WORDS 132   // ceil(8400/64)
#define CAP 32           // max (word,bits) entries per row
#define NBB 256          // kernel B blocks
#define NBA 525          // kernel A blocks: 8400 elems * 16 threads / 256

typedef unsigned long long u64;

// monotone-increasing float->u32 mapping
__device__ __forceinline__ unsigned mono_u32(float f) {
    unsigned u = __float_as_uint(f);
    return (u & 0x80000000u) ? ~u : (u | 0x80000000u);
}

// workspace layout (byte offsets)
#define WS_SLOGIT  0         // 8400*4 = 33600
#define WS_SBOX    33600     // 8400*16 = 134400 (16B aligned)
#define WS_CNT     168000    // 8400*4 = 33600
#define WS_ROWFLAG 201600    // 132*8 = 1056
#define WS_DONE    202656    // 4 (+pad)
#define WS_ENT     202672    // 8400*32*16 = 4300800 (16B aligned)

// ================= Kernel A: decode + rank + sorted scatter (out pre-masked) ============
// Every block redundantly builds all 8400 keys in LDS and ranks its 16 owned elements
// with 16 threads each.  Scan is manually 8x unrolled with 4 accumulators so 8 ds_read_b64
// are in flight per group (the #pragma-unroll version latency-chained at ~120cy/read).
// Leaders decode and write sorted arrays + out channels PRE-MASKED by valid (lg>0), so
// kernel B's tail only has to zero suppressed rows.
__global__ __launch_bounds__(256) void decode_rank_kernel(
        const float* __restrict__ score0, const float* __restrict__ bbox0, const float* __restrict__ kps0,
        const float* __restrict__ score1, const float* __restrict__ bbox1, const float* __restrict__ kps1,
        const float* __restrict__ score2, const float* __restrict__ bbox2, const float* __restrict__ kps2,
        float* __restrict__ s_logit, float* __restrict__ s_box,
        unsigned* __restrict__ cnt, u64* __restrict__ rowflag, unsigned* __restrict__ done_ctr,
        float* __restrict__ out) {
    __shared__ u64 keyL[N_TOT];
    const int tid = threadIdx.x;
    const int gtid = blockIdx.x * 256 + tid;

    // zero state for kernel B (kernel boundary guarantees visibility/order)
    if (gtid < N_TOT) cnt[gtid] = 0u;
    if (gtid < MASK_WORDS) rowflag[gtid] = 0ull;
    if (gtid == 0) *done_ctr = 0u;

    // build all 8400 keys in LDS (33 coalesced rounds; scores are L2-hot)
    for (int j = tid; j < N_TOT; j += 256) {
        const float* sc; int m;
        if (j < 6400)      { sc = score0; m = j; }
        else if (j < 8000) { sc = score1; m = j - 6400; }
        else               { sc = score2; m = j - 8000; }
        float lg = sc[m];
        // descending-logit order, ascending-index tie-break, one ascending u64 key
        keyL[j] = ((u64)(~mono_u32(lg)) << 14) | (u64)j;
    }
    __syncthreads();

    const int i = gtid >> 4;      // owned element (exactly 8400 groups)
    const int sub = tid & 15;     // 16 threads per element
    u64 ki = keyL[i];
    // stride-16 partition, manual 8x unroll, 4 accumulators -> 8 LDS reads in flight
    int r0 = 0, r1 = 0, r2 = 0, r3 = 0;
    int k = 0;
    for (; k < 520; k += 8) {
        u64 a0 = keyL[sub + ((k + 0) << 4)];
        u64 a1 = keyL[sub + ((k + 1) << 4)];
        u64 a2 = keyL[sub + ((k + 2) << 4)];
        u64 a3 = keyL[sub + ((k + 3) << 4)];
        u64 a4 = keyL[sub + ((k + 4) << 4)];
        u64 a5 = keyL[sub + ((k + 5) << 4)];
        u64 a6 = keyL[sub + ((k + 6) << 4)];
        u64 a7 = keyL[sub + ((k + 7) << 4)];
        r0 += (a0 < ki) ? 1 : 0;
        r1 += (a1 < ki) ? 1 : 0;
        r2 += (a2 < ki) ? 1 : 0;
        r3 += (a3 < ki) ? 1 : 0;
        r0 += (a4 < ki) ? 1 : 0;
        r1 += (a5 < ki) ? 1 : 0;
        r2 += (a6 < ki) ? 1 : 0;
        r3 += (a7 < ki) ? 1 : 0;
    }
    for (; k < 525; ++k) r0 += (keyL[sub + (k << 4)] < ki) ? 1 : 0;
    int rk = (r0 + r1) + (r2 + r3);
    rk += __shfl_xor(rk, 1);
    rk += __shfl_xor(rk, 2);
    rk += __shfl_xor(rk, 4);
    rk += __shfl_xor(rk, 8);

    if (sub == 0) {
        int r = rk;   // sorted position of element i
        const float *sc, *bb, *kp; int m, F; float s;
        if (i < 6400)      { sc=score0; bb=bbox0; kp=kps0; m=i;       F=80; s=8.f;  }
        else if (i < 8000) { sc=score1; bb=bbox1; kp=kps1; m=i-6400;  F=40; s=16.f; }
        else               { sc=score2; bb=bbox2; kp=kps2; m=i-8000;  F=20; s=32.f; }
        float px = (float)(m % F) * s;
        float py = (float)(m / F) * s;
        float lg = sc[m];
        bool valid = lg > 0.f;
        float mv = valid ? 1.f : 0.f;
        s_logit[r] = lg;
        float d0=bb[m*4+0]*s, d1=bb[m*4+1]*s, d2=bb[m*4+2]*s, d3=bb[m*4+3]*s;
        float x1 = px - d0, y1 = py - d1, x2 = px + d2, y2 = py + d3;
        ((float4*)s_box)[r] = make_float4(x1, y1, x2, y2);
        float* ob  = out;            // 8400*4
        float* os  = out + 33600;    // 8400
        float* okp = out + 42000;    // 8400*10
        float* om  = out + 126000;   // 8400
        ob[r*4+0]=x1*mv; ob[r*4+1]=y1*mv; ob[r*4+2]=x2*mv; ob[r*4+3]=y2*mv;
        os[r] = (1.0f / (1.0f + expf(-lg))) * mv;
        #pragma unroll
        for (int c = 0; c < 5; ++c) {
            okp[r*10 + 2*c]   = (px + kp[m*10 + 2*c]   * s) * mv;
            okp[r*10 + 2*c+1] = (py + kp[m*10 + 2*c+1] * s) * mv;
        }
        om[r] = mv;    // provisional: tail zeroes suppressed rows
    }
}

// ================= Kernel B: pairs + nms + suppressed-row zeroing =================
__global__ __launch_bounds__(256) void pairs_nms_kernel(
        const float* __restrict__ s_logit, const float* __restrict__ s_box,
        unsigned* __restrict__ cnt, ulonglong2* __restrict__ ent,
        u64* __restrict__ rowflag, unsigned* __restrict__ done_ctr,
        float* __restrict__ out) {
    __shared__ float4 cboxS[4][64];
    __shared__ float  careaS[4][64];
    __shared__ u64 vw_lds[MASK_WORDS];
    __shared__ u64 rem_lds[MASK_WORDS];
    __shared__ unsigned short wlist[MASK_WORDS];
    __shared__ int lastF;

    const int tid = threadIdx.x;
    const int wv = tid >> 6, lane = tid & 63;
    const int gw = blockIdx.x * 4 + wv;

    // ---- pairs: triangular wave-task loop ----
    for (int t = gw; t < 132 * 67; t += NBB * 4) {
        int x = t % 132, y = t / 132;
        int rb, cw;
        if (x + y < MASK_WORDS) { rb = x; cw = x + y; }
        else if (y == MASK_WORDS / 2) continue;      // wrapped y=66 duplicates direct
        else { rb = x + y - MASK_WORDS; cw = x; }

        int j = cw * 64 + lane;
        float4 cb = make_float4(0.f, 0.f, 0.f, 0.f);
        float lgj = -1.f;
        if (j < N_TOT) {
            cb = ((const float4*)s_box)[j];
            lgj = s_logit[j];
        }
        cboxS[wv][lane] = cb;              // wave-local LDS: in-order, no barrier
        careaS[wv][lane] = (cb.z - cb.x) * (cb.w - cb.y);
        u64 cvalid = __ballot(j < N_TOT && lgj > 0.f);
        if (cvalid == 0ull) continue;      // sorted => no valid columns here

        int r = rb * 64 + lane;
        float lgr = (r < N_TOT) ? s_logit[r] : -1.f;
        if (__ballot(lgr > 0.f) == 0ull) continue;

        u64 bits = 0ull;
        if (lgr > 0.f) {
            float4 rb4 = ((const float4*)s_box)[r];
            float rarea = (rb4.z - rb4.x) * (rb4.w - rb4.y);
            #pragma unroll 4
            for (int k = 0; k < 64; ++k) {
                float4 c4 = cboxS[wv][k];
                float ltx = fmaxf(rb4.x, c4.x);
                float lty = fmaxf(rb4.y, c4.y);
                float rbx = fminf(rb4.z, c4.z);
                float rby = fminf(rb4.w, c4.w);
                float w = fmaxf(rbx - ltx, 0.f);
                float h = fmaxf(rby - lty, 0.f);
                float inter = w * h;
                float iou = inter / (rarea + careaS[wv][k] - inter + 1e-9f);
                bits |= (iou > 0.4f) ? (1ull << k) : 0ull;
            }
            u64 m = cvalid;
            if (cw == rb) m &= (lane == 63) ? 0ull : (~0ull << (lane + 1));
            bits &= m;
        }
        if (bits) {
            unsigned idx = atomicAdd(&cnt[r], 1u);
            if (idx < CAP) {
                ulonglong2 e; e.x = bits; e.y = (u64)cw;
                ent[(size_t)r * CAP + idx] = e;
            }
            atomicOr(&rowflag[r >> 6], 1ull << (r & 63));
        }
    }

    // ---- completion counter: last block proceeds ----
    __threadfence();
    __syncthreads();
    if (tid == 0) {
        unsigned p = atomicAdd(done_ctr, 1u);
        lastF = (p == NBB - 1u) ? 1 : 0;
    }
    __syncthreads();
    if (!lastF) return;
    __threadfence();                       // acquire: other blocks' stores visible

    // build validw from s_logit (each wave handles 33 words via ballots)
    for (int q = wv * 33; q < wv * 33 + 33; ++q) {
        int row = q * 64 + lane;
        float lgq = (row < N_TOT) ? s_logit[row] : -1.f;
        u64 b = __ballot(lgq > 0.f);
        if (lane == 0) vw_lds[q] = b;
    }
    for (int q = tid; q < MASK_WORDS; q += 256) rem_lds[q] = 0ull;
    __syncthreads();

    // ---- word-serial greedy NMS on wave 0 ----
    // Stage loads are UNCONDITIONAL (no branch on loaded cnt -> no vmcnt stall in the
    // prefetch path); 4 entries inline; depth-3 rotation hides the ~900cy HBM latency.
    if (wv == 0) {
        u64 rf[3];
        #pragma unroll
        for (int s = 0; s < 3; ++s) {
            int w = s * 64 + lane;
            rf[s] = (w < MASK_WORDS) ? rowflag[w] : 0ull;
        }
        int base = 0;
        #pragma unroll
        for (int s = 0; s < 3; ++s) {
            bool nz = rf[s] != 0ull;
            u64 bal = __ballot(nz);
            int pos = __popcll(bal & ((1ull << lane) - 1ull));
            if (nz) wlist[base + pos] = (unsigned short)(s * 64 + lane);
            base += (int)__popcll(bal);
        }
        int n_w = base;

        int wdA=0, wdB=0, wdC=0;
        unsigned cA=0u, cB=0u, cC=0u;
        ulonglong2 A0,A1,A2,A3, B0,B1,B2,B3, C0,C1,C2,C3;
        A0.x=A0.y=A1.x=A1.y=A2.x=A2.y=A3.x=A3.y=0ull;
        B0=A0; B1=A0; B2=A0; B3=A0; C0=A0; C1=A0; C2=A0; C3=A0;

        #define LOADW(t, wd, c, e0, e1, e2, e3)                    \
            do {                                                   \
                wd = 0; c = 0u;                                    \
                if ((t) < n_w) {                                   \
                    wd = (int)wlist[t];                            \
                    int row_ = wd * 64 + lane;                     \
                    if (row_ < N_TOT) {                            \
                        const ulonglong2* ep_ = ent + (size_t)row_ * CAP; \
                        c  = cnt[row_];                            \
                        e0 = ep_[0];                               \
                        e1 = ep_[1];                               \
                        e2 = ep_[2];                               \
                        e3 = ep_[3];                               \
                    }                                              \
                }                                                  \
            } while (0)

        LOADW(0, wdA, cA, A0, A1, A2, A3);
        LOADW(1, wdB, cB, B0, B1, B2, B3);
        LOADW(2, wdC, cC, C0, C1, C2, C3);

        for (int t = 0; t < n_w; ++t) {
            int wdD; unsigned cD; ulonglong2 D0,D1,D2,D3;
            LOADW(t + 3, wdD, cD, D0, D1, D2, D3);   // depth-3 prefetch, branch-free

            // local (own-word) bits, computed AFTER data arrival with c-guards
            // (poisoned entries for e >= c are masked out by the guards)
            u64 lb = 0ull;
            lb |= (cA > 0u && (int)A0.y == wdA) ? A0.x : 0ull;
            lb |= (cA > 1u && (int)A1.y == wdA) ? A1.x : 0ull;
            lb |= (cA > 2u && (int)A2.y == wdA) ? A2.x : 0ull;
            lb |= (cA > 3u && (int)A3.y == wdA) ? A3.x : 0ull;
            if (cA > 4u) {                            // rare deep-overflow rows
                unsigned cm = min(cA, (unsigned)CAP);
                int row = wdA * 64 + lane;
                for (unsigned e = 4; e < cm; ++e) {
                    ulonglong2 g = ent[(size_t)row * CAP + e];
                    if ((int)g.y == wdA) lb |= g.x;
                }
            }

            u64 remw = rem_lds[wdA];                  // single wave: DS in-order
            u64 cand = __ballot(cA > 0u) & ~remw;
            if (cand) {
                u64 kept;
                u64 localmask = __ballot(lb != 0ull) & cand;
                if (localmask == 0ull) {
                    kept = cand;                      // common: no intra-word edges
                } else {
                    kept = 0ull;
                    u64 remw_new = remw;
                    u64 pend = cand;
                    while (pend) {
                        int b = __builtin_ctzll(pend);
                        pend &= pend - 1ull;
                        if (!((remw_new >> b) & 1ull)) {
                            kept |= 1ull << b;
                            unsigned lo = (unsigned)__builtin_amdgcn_readlane((int)(unsigned)lb, b);
                            unsigned hi = (unsigned)__builtin_amdgcn_readlane((int)(unsigned)(lb >> 32), b);
                            remw_new |= ((u64)hi << 32) | (u64)lo;
                            pend &= ~remw_new;
                        }
                    }
                    if (lane == 0) rem_lds[wdA] = remw_new;
                }
                if ((kept >> lane) & 1ull) {          // parallel far-edge application
                    if (cA > 0u) { int yw = (int)A0.y; if (yw != wdA) atomicOr(&rem_lds[yw], A0.x); }
                    if (cA > 1u) { int yw = (int)A1.y; if (yw != wdA) atomicOr(&rem_lds[yw], A1.x); }
                    if (cA > 2u) { int yw = (int)A2.y; if (yw != wdA) atomicOr(&rem_lds[yw], A2.x); }
                    if (cA > 3u) { int yw = (int)A3.y; if (yw != wdA) atomicOr(&rem_lds[yw], A3.x); }
                    if (cA > 4u) {
                        unsigned cm = min(cA, (unsigned)CAP);
                        int row = wdA * 64 + lane;
                        for (unsigned e = 4; e < cm; ++e) {
                            ulonglong2 g = ent[(size_t)row * CAP + e];
                            int yw = (int)g.y;
                            if (yw != wdA) atomicOr(&rem_lds[yw], g.x);
                        }
                    }
                }
            }
            wdA=wdB; cA=cB; A0=B0; A1=B1; A2=B2; A3=B3;
            wdB=wdC; cB=cC; B0=C0; B1=C1; B2=C2; B3=C3;
            wdC=wdD; cC=cD; C0=D0; C1=D1; C2=D2; C3=D3;
        }
        #undef LOADW
    }
    __syncthreads();

    // ---- finalize: zero only suppressed rows (valid & rem); rest already correct ----
    {
        float* ob  = out;            // 8400*4
        float* os  = out + 33600;    // 8400
        float* okp = out + 42000;    // 8400*10
        float* om  = out + 126000;   // 8400
        for (int r = tid; r < N_TOT; r += 256) {
            u64 both = vw_lds[r >> 6] & rem_lds[r >> 6];
            if ((both >> (r & 63)) & 1ull) {
                om[r] = 0.f;
                os[r] = 0.f;
                ((float4*)ob)[r] = make_float4(0.f, 0.f, 0.f, 0.f);
                #pragma unroll
                for (int c = 0; c < 10; ++c) okp[r*10 + c] = 0.f;
            }
        }
    }
}

extern "C" void kernel_launch(void* const* d_in, const int* in_sizes, int n_in,
                              void* d_out, int out_size, void* d_ws, size_t ws_size,
                              hipStream_t stream) {
    const float *score0, *bbox0, *kps0, *score1, *bbox1, *kps1, *score2, *bbox2, *kps2;
    if (in_sizes[1] == 25600) {
        score0 = (const float*)d_in[0]; bbox0 = (const float*)d_in[1]; kps0 = (const float*)d_in[2];
        score1 = (const float*)d_in[3]; bbox1 = (const float*)d_in[4]; kps1 = (const float*)d_in[5];
        score2 = (const float*)d_in[6]; bbox2 = (const float*)d_in[7]; kps2 = (const float*)d_in[8];
    } else {
        score0 = (const float*)d_in[0]; score1 = (const float*)d_in[1]; score2 = (const float*)d_in[2];
        bbox0  = (const float*)d_in[3]; bbox1  = (const float*)d_in[4]; bbox2  = (const float*)d_in[5];
        kps0   = (const float*)d_in[6]; kps1   = (const float*)d_in[7]; kps2   = (const float*)d_in[8];
    }

    char* ws = (char*)d_ws;
    float* s_logit      = (float*)(ws + WS_SLOGIT);
    float* s_box        = (float*)(ws + WS_SBOX);
    unsigned* cnt       = (unsigned*)(ws + WS_CNT);
    u64* rowflag        = (u64*)(ws + WS_ROWFLAG);
    unsigned* done_ctr  = (unsigned*)(ws + WS_DONE);
    ulonglong2* ent     = (ulonglong2*)(ws + WS_ENT);
    float* out = (float*)d_out;

    decode_rank_kernel<<<NBA, 256, 0, stream>>>(
        score0, bbox0, kps0, score1, bbox1, kps1, score2, bbox2, kps2,
        s_logit, s_box, cnt, rowflag, done_ctr, out);
    pairs_nms_kernel<<<NBB, 256, 0, stream>>>(
        s_logit, s_box, cnt, ent, rowflag, done_ctr, out);
}

// Round 5
// 143.087 us; speedup vs baseline: 1.8232x; 1.0342x over previous
//
#include <hip/hip_runtime.h>
#include <math.h>

#define N_TOT 8400
#define MASK_WORDS 132   // ceil(8400/64)
#define CAP 32           // max far (word,bits) entries per row
#define NBB 256          // kernel B blocks
#define NBA 525          // kernel A blocks: 8400 elems * 16 threads / 256

typedef unsigned long long u64;

// monotone-increasing float->u32 mapping
__device__ __forceinline__ unsigned mono_u32(float f) {
    unsigned u = __float_as_uint(f);
    return (u & 0x80000000u) ? ~u : (u | 0x80000000u);
}

// workspace layout (byte offsets, 16B aligned)
#define WS_SLOGIT  0         // 8400*4  = 33600
#define WS_SBOX    33600     // 8400*16 = 134400
#define WS_CNT     168000    // 8400*4  = 33600
#define WS_ROWFLAG 201600    // 132*8   = 1056
#define WS_DONE    202656    // 16
#define WS_DIAG    202672    // 8448*8  = 67584
#define WS_ENT     270256    // 8400*32*16 = 4300800

// ================= Kernel A: decode + rank + sorted scatter (out pre-masked) ============
// Every block builds all 8400 sort keys (u32 mono-float) in LDS and ranks its 16 owned
// elements with 16 threads each.  Ties (equal logits) resolved by ascending index via an
// explicit j<i term, so u32 keys suffice (4x less LDS traffic than u64, and 33.8KB LDS
// -> 4 blocks/CU).  Scan reads uint4 (4 keys per ds_read_b128), 132 reads/thread.
__global__ __launch_bounds__(256) void decode_rank_kernel(
        const float* __restrict__ score0, const float* __restrict__ bbox0, const float* __restrict__ kps0,
        const float* __restrict__ score1, const float* __restrict__ bbox1, const float* __restrict__ kps1,
        const float* __restrict__ score2, const float* __restrict__ bbox2, const float* __restrict__ kps2,
        float* __restrict__ s_logit, float* __restrict__ s_box,
        unsigned* __restrict__ cnt, u64* __restrict__ rowflag, unsigned* __restrict__ done_ctr,
        float* __restrict__ out) {
    __shared__ __align__(16) unsigned keyL[8448];
    const int tid = threadIdx.x;
    const int gtid = blockIdx.x * 256 + tid;

    // zero state for kernel B (kernel boundary guarantees visibility)
    if (gtid < N_TOT) cnt[gtid] = 0u;
    if (gtid < MASK_WORDS) rowflag[gtid] = 0ull;
    if (gtid == 0) *done_ctr = 0u;

    // build all keys in LDS; pad [8400,8448) with 0 (never counts: 0 = -NaN image,
    // unreachable from normal logits; even on collision the j<i tie term rejects pads)
    for (int j = tid; j < 8448; j += 256) {
        unsigned kk = 0u;
        if (j < N_TOT) {
            const float* sc; int m;
            if (j < 6400)      { sc = score0; m = j; }
            else if (j < 8000) { sc = score1; m = j - 6400; }
            else               { sc = score2; m = j - 8000; }
            kk = mono_u32(sc[m]);
        }
        keyL[j] = kk;
    }
    __syncthreads();

    const int i = gtid >> 4;      // owned element
    const int sub = tid & 15;     // 16 threads per element
    const unsigned ki = keyL[i];
    const uint4* kv = (const uint4*)keyL;
    const int jb = sub << 2;      // element index of .x at k: jb + (k<<6)
    int rk0 = 0, rk1 = 0, rk2 = 0, rk3 = 0;

#define ACC(v, j0, acc) do {                                   \
        acc += ((v).x > ki) ? 1 : 0;                           \
        acc += (((v).x == ki) && ((j0) + 0 < i)) ? 1 : 0;      \
        acc += ((v).y > ki) ? 1 : 0;                           \
        acc += (((v).y == ki) && ((j0) + 1 < i)) ? 1 : 0;      \
        acc += ((v).z > ki) ? 1 : 0;                           \
        acc += (((v).z == ki) && ((j0) + 2 < i)) ? 1 : 0;      \
        acc += ((v).w > ki) ? 1 : 0;                           \
        acc += (((v).w == ki) && ((j0) + 3 < i)) ? 1 : 0;      \
    } while (0)

    for (int k = 0; k < 132; k += 4) {
        uint4 va = kv[sub + ((k + 0) << 4)];
        uint4 vb = kv[sub + ((k + 1) << 4)];
        uint4 vc = kv[sub + ((k + 2) << 4)];
        uint4 vd = kv[sub + ((k + 3) << 4)];
        ACC(va, jb + ((k + 0) << 6), rk0);
        ACC(vb, jb + ((k + 1) << 6), rk1);
        ACC(vc, jb + ((k + 2) << 6), rk2);
        ACC(vd, jb + ((k + 3) << 6), rk3);
    }
#undef ACC
    int rk = (rk0 + rk1) + (rk2 + rk3);
    rk += __shfl_xor(rk, 1);
    rk += __shfl_xor(rk, 2);
    rk += __shfl_xor(rk, 4);
    rk += __shfl_xor(rk, 8);

    if (sub == 0) {
        int r = rk;   // sorted position of element i (rank among descending logits)
        const float *sc, *bb, *kp; int m, F; float s;
        if (i < 6400)      { sc=score0; bb=bbox0; kp=kps0; m=i;       F=80; s=8.f;  }
        else if (i < 8000) { sc=score1; bb=bbox1; kp=kps1; m=i-6400;  F=40; s=16.f; }
        else               { sc=score2; bb=bbox2; kp=kps2; m=i-8000;  F=20; s=32.f; }
        float px = (float)(m % F) * s;
        float py = (float)(m / F) * s;
        float lg = sc[m];
        float mv = (lg > 0.f) ? 1.f : 0.f;
        s_logit[r] = lg;
        float d0=bb[m*4+0]*s, d1=bb[m*4+1]*s, d2=bb[m*4+2]*s, d3=bb[m*4+3]*s;
        float x1 = px - d0, y1 = py - d1, x2 = px + d2, y2 = py + d3;
        ((float4*)s_box)[r] = make_float4(x1, y1, x2, y2);
        float* ob  = out;            // 8400*4
        float* os  = out + 33600;    // 8400
        float* okp = out + 42000;    // 8400*10
        float* om  = out + 126000;   // 8400
        ob[r*4+0]=x1*mv; ob[r*4+1]=y1*mv; ob[r*4+2]=x2*mv; ob[r*4+3]=y2*mv;
        os[r] = (1.0f / (1.0f + expf(-lg))) * mv;
        #pragma unroll
        for (int c = 0; c < 5; ++c) {
            okp[r*10 + 2*c]   = (px + kp[m*10 + 2*c]   * s) * mv;
            okp[r*10 + 2*c+1] = (py + kp[m*10 + 2*c+1] * s) * mv;
        }
        om[r] = mv;    // provisional; tail zeroes suppressed rows
    }
}

// ================= Kernel B: pairs + word-serial NMS + suppressed-row zeroing ==========
__global__ __launch_bounds__(256) void pairs_nms_kernel(
        const float* __restrict__ s_logit, const float* __restrict__ s_box,
        unsigned* __restrict__ cnt, ulonglong2* __restrict__ ent,
        u64* __restrict__ diag,
        u64* __restrict__ rowflag, unsigned* __restrict__ done_ctr,
        float* __restrict__ out) {
    __shared__ float4 cboxS[4][64];
    __shared__ float  careaS[4][64];
    __shared__ u64 rem_lds[MASK_WORDS];
    __shared__ unsigned short wlist[MASK_WORDS];
    __shared__ int lastF;

    const int tid = threadIdx.x;
    const int wv = tid >> 6, lane = tid & 63;
    const int gw = blockIdx.x * 4 + wv;

    // ---- pairs: triangular wave-task loop ----
    // Diagonal tasks (rb==cw) store own-word successor-overlap bits to diag[] (plain
    // store, ALL rows incl. zero bits) instead of cnt/ent; off-diagonal entries are
    // therefore pure-far (target word strictly greater than own word).
    for (int t = gw; t < 132 * 67; t += NBB * 4) {
        int x = t % 132, y = t / 132;
        int rb, cw;
        if (x + y < MASK_WORDS) { rb = x; cw = x + y; }
        else if (y == MASK_WORDS / 2) continue;      // wrapped y=66 duplicates direct
        else { rb = x + y - MASK_WORDS; cw = x; }
        bool isdiag = (rb == cw);

        int j = cw * 64 + lane;
        float4 cb = make_float4(0.f, 0.f, 0.f, 0.f);
        float lgj = -1.f;
        if (j < N_TOT) {
            cb = ((const float4*)s_box)[j];
            lgj = s_logit[j];
        }
        cboxS[wv][lane] = cb;              // wave-local LDS: in-order, no barrier
        careaS[wv][lane] = (cb.z - cb.x) * (cb.w - cb.y);
        u64 cvalid = __ballot(j < N_TOT && lgj > 0.f);
        if (!isdiag && cvalid == 0ull) continue;     // sorted => no valid cols here

        int r = rb * 64 + lane;
        float lgr = isdiag ? lgj : ((r < N_TOT) ? s_logit[r] : -1.f);
        if (!isdiag && __ballot(lgr > 0.f) == 0ull) continue;

        u64 bits = 0ull;
        if (cvalid != 0ull && lgr > 0.f) {
            float4 rb4 = isdiag ? cb : ((const float4*)s_box)[r];
            float rarea = (rb4.z - rb4.x) * (rb4.w - rb4.y);
            #pragma unroll 4
            for (int k = 0; k < 64; ++k) {
                float4 c4 = cboxS[wv][k];
                float ltx = fmaxf(rb4.x, c4.x);
                float lty = fmaxf(rb4.y, c4.y);
                float rbx = fminf(rb4.z, c4.z);
                float rby = fminf(rb4.w, c4.w);
                float w = fmaxf(rbx - ltx, 0.f);
                float h = fmaxf(rby - lty, 0.f);
                float inter = w * h;
                float iou = inter / (rarea + careaS[wv][k] - inter + 1e-9f);
                bits |= (iou > 0.4f) ? (1ull << k) : 0ull;
            }
            u64 m = cvalid;
            if (isdiag) m &= (lane == 63) ? 0ull : (~0ull << (lane + 1));
            bits &= m;
        }
        if (isdiag) {
            if (r < N_TOT) diag[r] = bits;           // unconditional (incl. zero)
            if (bits) atomicOr(&rowflag[r >> 6], 1ull << (r & 63));
            continue;
        }
        if (bits) {
            unsigned idx = atomicAdd(&cnt[r], 1u);
            if (idx < CAP) {
                ulonglong2 e; e.x = bits; e.y = (u64)cw;
                ent[(size_t)r * CAP + idx] = e;
            }
            atomicOr(&rowflag[r >> 6], 1ull << (r & 63));
        }
    }

    // ---- completion counter: last block proceeds ----
    __threadfence();
    __syncthreads();
    if (tid == 0) {
        unsigned p = atomicAdd(done_ctr, 1u);
        lastF = (p == NBB - 1u) ? 1 : 0;
    }
    __syncthreads();
    if (!lastF) return;
    __threadfence();                       // acquire: other blocks' stores visible

    for (int q = tid; q < MASK_WORDS; q += 256) rem_lds[q] = 0ull;
    __syncthreads();

    // ---- word-serial greedy NMS on wave 0 ----
    // Per word: cand = (rows with any edge) & ~rem.  Serial resolution iterates ONLY
    // over sources S = cand & ballot(diag-bits != 0) (~3-5 bits), since only sources
    // modify the local rem word; all other cand bits are then kept iff not locally
    // suppressed (kept = cand & ~rn; exact: local suppressors have lower bit index).
    // 3-stage modulo-scheduled pipeline -> no register rotation moves, loads 3 ahead.
    if (wv == 0) {
        u64 rf[3];
        #pragma unroll
        for (int s = 0; s < 3; ++s) {
            int w = s * 64 + lane;
            rf[s] = (w < MASK_WORDS) ? rowflag[w] : 0ull;
        }
        int base = 0;
        #pragma unroll
        for (int s = 0; s < 3; ++s) {
            bool nz = rf[s] != 0ull;
            u64 bal = __ballot(nz);
            int pos = __popcll(bal & ((1ull << lane) - 1ull));
            if (nz) wlist[base + pos] = (unsigned short)(s * 64 + lane);
            base += (int)__popcll(bal);
        }
        int n_w = base;

        int wdA=0, wdB=0, wdC=0;
        unsigned cA=0u, cB=0u, cC=0u;
        u64 lbA=0ull, lbB=0ull, lbC=0ull;
        ulonglong2 A0,A1,A2,A3, B0,B1,B2,B3, C0,C1,C2,C3;
        A0.x=A0.y=0ull; A1=A0; A2=A0; A3=A0;
        B0=A0; B1=A0; B2=A0; B3=A0; C0=A0; C1=A0; C2=A0; C3=A0;

#define LOADST(t, wd, c, lb, e0, e1, e2, e3) do {              \
        wd = 0; c = 0u; lb = 0ull;                             \
        if ((t) < n_w) {                                       \
            wd = (int)wlist[t];                                \
            int row_ = wd * 64 + lane;                         \
            if (row_ < N_TOT) {                                \
                const ulonglong2* ep_ = ent + (size_t)row_ * CAP; \
                c  = cnt[row_];                                \
                lb = diag[row_];                               \
                e0 = ep_[0];                                   \
                e1 = ep_[1];                                   \
                e2 = ep_[2];                                   \
                e3 = ep_[3];                                   \
            }                                                  \
        }                                                      \
    } while (0)

#define STEP(wd, c, lb, e0, e1, e2, e3, TNEXT) do {            \
        u64 remw = rem_lds[wd];                                \
        u64 cand = __ballot(c > 0u || lb != 0ull) & ~remw;     \
        if (cand) {                                            \
            u64 kept;                                          \
            u64 S = __ballot(lb != 0ull) & cand;               \
            if (S == 0ull) {                                   \
                kept = cand;                                   \
            } else {                                           \
                u64 rn = remw;                                 \
                u64 pend = S;                                  \
                while (pend) {                                 \
                    int b_ = __builtin_ctzll(pend);            \
                    pend &= pend - 1ull;                       \
                    if (!((rn >> b_) & 1ull)) {                \
                        unsigned lo_ = (unsigned)__builtin_amdgcn_readlane((int)(unsigned)lb, b_); \
                        unsigned hi_ = (unsigned)__builtin_amdgcn_readlane((int)(unsigned)(lb >> 32), b_); \
                        rn |= ((u64)hi_ << 32) | (u64)lo_;     \
                        pend &= ~rn;                           \
                    }                                          \
                }                                              \
                kept = cand & ~rn;                             \
                if (lane == 0) rem_lds[wd] = rn;               \
            }                                                  \
            bool kp_ = (kept >> lane) & 1ull;                  \
            if (kp_) {                                         \
                if (c > 0u) atomicOr(&rem_lds[(int)e0.y], e0.x); \
                if (c > 1u) atomicOr(&rem_lds[(int)e1.y], e1.x); \
                if (c > 2u) atomicOr(&rem_lds[(int)e2.y], e2.x); \
                if (c > 3u) atomicOr(&rem_lds[(int)e3.y], e3.x); \
            }                                                  \
            if (__ballot(kp_ && c > 4u)) {                     \
                if (kp_ && c > 4u) {                           \
                    unsigned cm_ = min(c, (unsigned)CAP);      \
                    int row_ = wd * 64 + lane;                 \
                    for (unsigned e_ = 4; e_ < cm_; ++e_) {    \
                        ulonglong2 g_ = ent[(size_t)row_ * CAP + e_]; \
                        atomicOr(&rem_lds[(int)g_.y], g_.x);   \
                    }                                          \
                }                                              \
            }                                                  \
        }                                                      \
        LOADST(TNEXT, wd, c, lb, e0, e1, e2, e3);              \
    } while (0)

        if (n_w > 0) {
            LOADST(0, wdA, cA, lbA, A0, A1, A2, A3);
            LOADST(1, wdB, cB, lbB, B0, B1, B2, B3);
            LOADST(2, wdC, cC, lbC, C0, C1, C2, C3);
            int t = 0;
            while (true) {
                STEP(wdA, cA, lbA, A0, A1, A2, A3, t + 3); if (++t >= n_w) break;
                STEP(wdB, cB, lbB, B0, B1, B2, B3, t + 3); if (++t >= n_w) break;
                STEP(wdC, cC, lbC, C0, C1, C2, C3, t + 3); if (++t >= n_w) break;
            }
        }
#undef STEP
#undef LOADST
    }
    __syncthreads();

    // ---- finalize: zero only suppressed rows (rem bits are valid-masked already) ----
    {
        float* ob  = out;            // 8400*4
        float* os  = out + 33600;    // 8400
        float* okp = out + 42000;    // 8400*10
        float* om  = out + 126000;   // 8400
        for (int r = tid; r < N_TOT; r += 256) {
            if ((rem_lds[r >> 6] >> (r & 63)) & 1ull) {
                om[r] = 0.f;
                os[r] = 0.f;
                ((float4*)ob)[r] = make_float4(0.f, 0.f, 0.f, 0.f);
                #pragma unroll
                for (int c = 0; c < 10; ++c) okp[r*10 + c] = 0.f;
            }
        }
    }
}

extern "C" void kernel_launch(void* const* d_in, const int* in_sizes, int n_in,
                              void* d_out, int out_size, void* d_ws, size_t ws_size,
                              hipStream_t stream) {
    const float *score0, *bbox0, *kps0, *score1, *bbox1, *kps1, *score2, *bbox2, *kps2;
    if (in_sizes[1] == 25600) {
        score0 = (const float*)d_in[0]; bbox0 = (const float*)d_in[1]; kps0 = (const float*)d_in[2];
        score1 = (const float*)d_in[3]; bbox1 = (const float*)d_in[4]; kps1 = (const float*)d_in[5];
        score2 = (const float*)d_in[6]; bbox2 = (const float*)d_in[7]; kps2 = (const float*)d_in[8];
    } else {
        score0 = (const float*)d_in[0]; score1 = (const float*)d_in[1]; score2 = (const float*)d_in[2];
        bbox0  = (const float*)d_in[3]; bbox1  = (const float*)d_in[4]; bbox2  = (const float*)d_in[5];
        kps0   = (const float*)d_in[6]; kps1   = (const float*)d_in[7]; kps2   = (const float*)d_in[8];
    }

    char* ws = (char*)d_ws;
    float* s_logit      = (float*)(ws + WS_SLOGIT);
    float* s_box        = (float*)(ws + WS_SBOX);
    unsigned* cnt       = (unsigned*)(ws + WS_CNT);
    u64* rowflag        = (u64*)(ws + WS_ROWFLAG);
    unsigned* done_ctr  = (unsigned*)(ws + WS_DONE);
    u64* diag           = (u64*)(ws + WS_DIAG);
    ulonglong2* ent     = (ulonglong2*)(ws + WS_ENT);
    float* out = (float*)d_out;

    decode_rank_kernel<<<NBA, 256, 0, stream>>>(
        score0, bbox0, kps0, score1, bbox1, kps1, score2, bbox2, kps2,
        s_logit, s_box, cnt, rowflag, done_ctr, out);
    pairs_nms_kernel<<<NBB, 256, 0, stream>>>(
        s_logit, s_box, cnt, ent, diag, rowflag, done_ctr, out);
}

// Round 6
// 111.270 us; speedup vs baseline: 2.3445x; 1.2859x over previous
//
#include <hip/hip_runtime.h>
#include <math.h>

#define N_TOT 8400
#define MASK_WORDS 132   // ceil(8400/64)
#define CAP 32           // max far (word,bits) entries per row
#define RT 33            // rank tiles: ceil(8400/256)

typedef unsigned long long u64;

// monotone-increasing float->u32 mapping
__device__ __forceinline__ unsigned mono_u32(float f) {
    unsigned u = __float_as_uint(f);
    return (u & 0x80000000u) ? ~u : (u | 0x80000000u);
}

// ---------------- K1: decode all 3 scales + build sort keys + zero-init state ----------------
__global__ void decode_kernel(const float* __restrict__ score0, const float* __restrict__ bbox0, const float* __restrict__ kps0,
                              const float* __restrict__ score1, const float* __restrict__ bbox1, const float* __restrict__ kps1,
                              const float* __restrict__ score2, const float* __restrict__ bbox2, const float* __restrict__ kps2,
                              float* __restrict__ logit, float* __restrict__ sig,
                              float* __restrict__ box, float* __restrict__ kps,
                              u64* __restrict__ key, int* __restrict__ rank,
                              unsigned int* __restrict__ cnt,
                              u64* __restrict__ validw, u64* __restrict__ rowflag) {
    int i = blockIdx.x * blockDim.x + threadIdx.x;
    if (i >= N_TOT) return;
    if (i < MASK_WORDS) { validw[i] = 0ull; rowflag[i] = 0ull; }
    rank[i] = 0;
    cnt[i] = 0u;
    const float *sc, *bb, *kp;
    int m, F; float s;
    if (i < 6400)      { sc = score0; bb = bbox0; kp = kps0; m = i;        F = 80; s = 8.f;  }
    else if (i < 8000) { sc = score1; bb = bbox1; kp = kps1; m = i - 6400; F = 40; s = 16.f; }
    else               { sc = score2; bb = bbox2; kp = kps2; m = i - 8000; F = 20; s = 32.f; }
    float px = (float)(m % F) * s;
    float py = (float)(m / F) * s;
    float lg = sc[m];
    logit[i] = lg;
    sig[i] = 1.0f / (1.0f + expf(-lg));
    // descending-logit order with ascending-index tie-break, as one u64 key (ascending)
    key[i] = ((u64)(~mono_u32(lg)) << 14) | (u64)i;
    float d0 = bb[m*4+0]*s, d1 = bb[m*4+1]*s, d2 = bb[m*4+2]*s, d3 = bb[m*4+3]*s;
    box[i*4+0] = px - d0;
    box[i*4+1] = py - d1;
    box[i*4+2] = px + d2;
    box[i*4+3] = py + d3;
    #pragma unroll
    for (int c = 0; c < 5; ++c) {
        kps[i*10 + 2*c]   = px + kp[m*10 + 2*c]   * s;
        kps[i*10 + 2*c+1] = py + kp[m*10 + 2*c+1] * s;
    }
}

// ---------------- K2: tiled rank = #{j : key[j] < key[i]} ----------------
__global__ __launch_bounds__(256) void rank_kernel(const u64* __restrict__ key, int* __restrict__ rank) {
    __shared__ u64 tile[256];
    int i = blockIdx.x * 256 + threadIdx.x;
    int t0 = blockIdx.y * 256;
    u64 ki = (i < N_TOT) ? key[i] : 0ull;
    int j = t0 + threadIdx.x;
    tile[threadIdx.x] = (j < N_TOT) ? key[j] : ~0ull;   // OOB sorts last (never < ki)
    __syncthreads();
    if (i >= N_TOT) return;
    int rk = 0;
    #pragma unroll 8
    for (int k = 0; k < 256; ++k) rk += (tile[k] < ki) ? 1 : 0;
    if (rk) atomicAdd(&rank[i], rk);
}

// ---------------- K3: scatter into sorted order + set valid bits ----------------
__global__ void scatter_kernel(const int* __restrict__ rank,
                               const float* __restrict__ logit, const float* __restrict__ sig,
                               const float* __restrict__ box, const float* __restrict__ kps,
                               float* __restrict__ s_logit, float* __restrict__ s_sig,
                               float* __restrict__ s_box, float* __restrict__ s_kps,
                               u64* __restrict__ validw) {
    int i = blockIdx.x * blockDim.x + threadIdx.x;
    if (i >= N_TOT) return;
    int r = rank[i];
    float lg = logit[i];
    s_logit[r] = lg;
    s_sig[r] = sig[i];
    #pragma unroll
    for (int c = 0; c < 4; ++c)  s_box[r*4+c] = box[i*4+c];
    #pragma unroll
    for (int c = 0; c < 10; ++c) s_kps[r*10+c] = kps[i*10+c];
    if (lg > 0.f) atomicOr(&validw[r >> 6], 1ull << (r & 63));
}

// ---------------- K4: triangular pairs; diagonal -> diag[] channel, off-diag -> ent[] ----------------
// Triangular launch: grid (132, 67); wrap-map covers exactly {(rb,cw): 0<=rb<=cw<132}.
// Diagonal tasks (rb==cw) store own-word successor-overlap bits into diag[] (plain store,
// ALL rows incl. zero), so off-diagonal ent[] entries are pure-far (target word > own word).
__global__ __launch_bounds__(64) void pairs_kernel(const float* __restrict__ s_logit,
                                                   const float* __restrict__ s_box,
                                                   unsigned int* __restrict__ cnt,
                                                   ulonglong2* __restrict__ ent,
                                                   u64* __restrict__ diag,
                                                   u64* __restrict__ rowflag) {
    int x = blockIdx.x;   // 0..131
    int y = blockIdx.y;   // 0..66
    int rb, cw;
    if (x + y < MASK_WORDS) { rb = x; cw = x + y; }
    else {
        if (y == MASK_WORDS / 2) return;    // wrapped y=66 duplicates direct y=66
        rb = x + y - MASK_WORDS; cw = x;
    }
    bool isdiag = (rb == cw);
    int tid = threadIdx.x;

    __shared__ float4 cbox[64];
    __shared__ float  carea[64];
    int j = cw * 64 + tid;
    float4 cb = make_float4(0.f, 0.f, 0.f, 0.f);
    float lgj = -1.f;
    if (j < N_TOT) {
        cb = ((const float4*)s_box)[j];
        lgj = s_logit[j];
    }
    cbox[tid] = cb;                    // single wave: DS in-order, no barrier needed
    carea[tid] = (cb.z - cb.x) * (cb.w - cb.y);
    u64 cvalid = __ballot(j < N_TOT && lgj > 0.f);
    if (!isdiag && cvalid == 0ull) return;     // sorted => no valid columns here

    int r = rb * 64 + tid;
    float lgr = isdiag ? lgj : ((r < N_TOT) ? s_logit[r] : -1.f);
    if (!isdiag && __ballot(lgr > 0.f) == 0ull) return;

    u64 bits = 0ull;
    if (cvalid != 0ull && lgr > 0.f) {
        float4 rb4 = isdiag ? cb : ((const float4*)s_box)[r];
        float rarea = (rb4.z - rb4.x) * (rb4.w - rb4.y);
        #pragma unroll 4
        for (int k = 0; k < 64; ++k) {
            float4 c4 = cbox[k];
            float ltx = fmaxf(rb4.x, c4.x);
            float lty = fmaxf(rb4.y, c4.y);
            float rbx = fminf(rb4.z, c4.z);
            float rby = fminf(rb4.w, c4.w);
            float w = fmaxf(rbx - ltx, 0.f);
            float h = fmaxf(rby - lty, 0.f);
            float inter = w * h;
            float iou = inter / (rarea + carea[k] - inter + 1e-9f);
            bits |= (iou > 0.4f) ? (1ull << k) : 0ull;
        }
        u64 m = cvalid;
        if (isdiag) m &= (tid == 63) ? 0ull : (~0ull << (tid + 1));  // strict successors
        bits &= m;
    }
    if (isdiag) {
        if (r < N_TOT) diag[r] = bits;         // unconditional (incl. zero)
        if (bits) atomicOr(&rowflag[r >> 6], 1ull << (r & 63));
        return;
    }
    if (bits) {
        unsigned idx = atomicAdd(&cnt[r], 1u);
        if (idx < CAP) {
            ulonglong2 e; e.x = bits; e.y = (u64)cw;
            ent[(size_t)r * CAP + idx] = e;
        }
        atomicOr(&rowflag[r >> 6], 1ull << (r & 63));
    }
}

// ---------------- K5: word-serial greedy resolve (one wave) ----------------
// Per word: cand = (rows with any edge) & ~rem.  Serial resolution iterates ONLY over
// sources S = cand & ballot(diag != 0) (~few bits); spectators resolved by
// kept = cand & ~rn (exact: local suppressors have lower bit index).  3-deep
// branch-free prefetch (cnt + diag + 4 ent entries unconditional per stage).
__global__ __launch_bounds__(64) void nms_kernel(const u64* __restrict__ rowflag_g,
                                                 const u64* __restrict__ validw_g,
                                                 const unsigned int* __restrict__ cnt_g,
                                                 const u64* __restrict__ diag_g,
                                                 const ulonglong2* __restrict__ ent_g,
                                                 u64* __restrict__ keep_words) {
    __shared__ u64 rem_lds[MASK_WORDS];
    __shared__ unsigned short wlist[MASK_WORDS];
    int lane = threadIdx.x;

    u64 rf[3], vw[3];
    #pragma unroll
    for (int s = 0; s < 3; ++s) {
        int w = s * 64 + lane;
        rf[s] = (w < MASK_WORDS) ? rowflag_g[w] : 0ull;
        vw[s] = (w < MASK_WORDS) ? validw_g[w] : 0ull;
        if (w < MASK_WORDS) rem_lds[w] = 0ull;
    }

    // sorted list of words containing >=1 edge-row
    int base = 0;
    #pragma unroll
    for (int s = 0; s < 3; ++s) {
        bool nz = rf[s] != 0ull;
        u64 bal = __ballot(nz);
        int pos = __popcll(bal & ((1ull << lane) - 1ull));
        if (nz) wlist[base + pos] = (unsigned short)(s * 64 + lane);
        base += (int)__popcll(bal);
    }
    int n_w = base;

    int wdA=0, wdB=0, wdC=0;
    unsigned cA=0u, cB=0u, cC=0u;
    u64 lbA=0ull, lbB=0ull, lbC=0ull;
    ulonglong2 A0,A1,A2,A3, B0,B1,B2,B3, C0,C1,C2,C3;
    A0.x=A0.y=0ull; A1=A0; A2=A0; A3=A0;
    B0=A0; B1=A0; B2=A0; B3=A0; C0=A0; C1=A0; C2=A0; C3=A0;

#define LOADST(t, wd, c, lb, e0, e1, e2, e3) do {              \
        wd = 0; c = 0u; lb = 0ull;                             \
        if ((t) < n_w) {                                       \
            wd = (int)wlist[t];                                \
            int row_ = wd * 64 + lane;                         \
            if (row_ < N_TOT) {                                \
                const ulonglong2* ep_ = ent_g + (size_t)row_ * CAP; \
                c  = cnt_g[row_];                              \
                lb = diag_g[row_];                             \
                e0 = ep_[0];                                   \
                e1 = ep_[1];                                   \
                e2 = ep_[2];                                   \
                e3 = ep_[3];                                   \
            }                                                  \
        }                                                      \
    } while (0)

#define STEP(wd, c, lb, e0, e1, e2, e3, TNEXT) do {            \
        u64 remw = rem_lds[wd];                                \
        u64 cand = __ballot(c > 0u || lb != 0ull) & ~remw;     \
        if (cand) {                                            \
            u64 kept;                                          \
            u64 S = __ballot(lb != 0ull) & cand;               \
            if (S == 0ull) {                                   \
                kept = cand;                                   \
            } else {                                           \
                u64 rn = remw;                                 \
                u64 pend = S;                                  \
                while (pend) {                                 \
                    int b_ = __builtin_ctzll(pend);            \
                    pend &= pend - 1ull;                       \
                    if (!((rn >> b_) & 1ull)) {                \
                        unsigned lo_ = (unsigned)__builtin_amdgcn_readlane((int)(unsigned)lb, b_); \
                        unsigned hi_ = (unsigned)__builtin_amdgcn_readlane((int)(unsigned)(lb >> 32), b_); \
                        rn |= ((u64)hi_ << 32) | (u64)lo_;     \
                        pend &= ~rn;                           \
                    }                                          \
                }                                              \
                kept = cand & ~rn;                             \
                if (lane == 0) rem_lds[wd] = rn;               \
            }                                                  \
            bool kp_ = (kept >> lane) & 1ull;                  \
            if (kp_) {                                         \
                if (c > 0u) atomicOr(&rem_lds[(int)e0.y], e0.x); \
                if (c > 1u) atomicOr(&rem_lds[(int)e1.y], e1.x); \
                if (c > 2u) atomicOr(&rem_lds[(int)e2.y], e2.x); \
                if (c > 3u) atomicOr(&rem_lds[(int)e3.y], e3.x); \
            }                                                  \
            if (__ballot(kp_ && c > 4u)) {                     \
                if (kp_ && c > 4u) {                           \
                    unsigned cm_ = min(c, (unsigned)CAP);      \
                    int row_ = wd * 64 + lane;                 \
                    for (unsigned e_ = 4; e_ < cm_; ++e_) {    \
                        ulonglong2 g_ = ent_g[(size_t)row_ * CAP + e_]; \
                        atomicOr(&rem_lds[(int)g_.y], g_.x);   \
                    }                                          \
                }                                              \
            }                                                  \
        }                                                      \
        LOADST(TNEXT, wd, c, lb, e0, e1, e2, e3);              \
    } while (0)

    if (n_w > 0) {
        LOADST(0, wdA, cA, lbA, A0, A1, A2, A3);
        LOADST(1, wdB, cB, lbB, B0, B1, B2, B3);
        LOADST(2, wdC, cC, lbC, C0, C1, C2, C3);
        int t = 0;
        while (true) {
            STEP(wdA, cA, lbA, A0, A1, A2, A3, t + 3); if (++t >= n_w) break;
            STEP(wdB, cB, lbB, B0, B1, B2, B3, t + 3); if (++t >= n_w) break;
            STEP(wdC, cC, lbC, C0, C1, C2, C3, t + 3); if (++t >= n_w) break;
        }
    }
#undef STEP
#undef LOADST

    #pragma unroll
    for (int s = 0; s < 3; ++s) {
        int w = s * 64 + lane;
        if (w < MASK_WORDS) keep_words[w] = vw[s] & ~rem_lds[w];
    }
}

// ---------------- K6: write outputs ----------------
__global__ void output_kernel(const float* __restrict__ s_sig, const float* __restrict__ s_box,
                              const float* __restrict__ s_kps,
                              const u64* __restrict__ keep_words,
                              float* __restrict__ out) {
    int r = blockIdx.x * blockDim.x + threadIdx.x;
    if (r >= N_TOT) return;
    float m = ((keep_words[r >> 6] >> (r & 63)) & 1ull) ? 1.0f : 0.0f;
    float* ob = out;                   // 8400*4
    float* os = out + 33600;           // 8400
    float* okp = out + 42000;          // 8400*10
    float* om = out + 126000;          // 8400
    #pragma unroll
    for (int c = 0; c < 4; ++c)  ob[r*4+c] = s_box[r*4+c] * m;
    os[r] = s_sig[r] * m;
    #pragma unroll
    for (int c = 0; c < 10; ++c) okp[r*10+c] = s_kps[r*10+c] * m;
    om[r] = m;
}

extern "C" void kernel_launch(void* const* d_in, const int* in_sizes, int n_in,
                              void* d_out, int out_size, void* d_ws, size_t ws_size,
                              hipStream_t stream) {
    const float *score0, *bbox0, *kps0, *score1, *bbox1, *kps1, *score2, *bbox2, *kps2;
    if (in_sizes[1] == 25600) {
        score0 = (const float*)d_in[0]; bbox0 = (const float*)d_in[1]; kps0 = (const float*)d_in[2];
        score1 = (const float*)d_in[3]; bbox1 = (const float*)d_in[4]; kps1 = (const float*)d_in[5];
        score2 = (const float*)d_in[6]; bbox2 = (const float*)d_in[7]; kps2 = (const float*)d_in[8];
    } else {
        score0 = (const float*)d_in[0]; score1 = (const float*)d_in[1]; score2 = (const float*)d_in[2];
        bbox0  = (const float*)d_in[3]; bbox1  = (const float*)d_in[4]; bbox2  = (const float*)d_in[5];
        kps0   = (const float*)d_in[6]; kps1   = (const float*)d_in[7]; kps2   = (const float*)d_in[8];
    }

    char* ws = (char*)d_ws;
    float* logit   = (float*)(ws + 0);
    float* sig     = (float*)(ws + 33600);
    float* box     = (float*)(ws + 67200);
    float* kps     = (float*)(ws + 201600);
    int*   rank    = (int*)  (ws + 537600);
    float* s_logit = (float*)(ws + 571200);
    float* s_sig   = (float*)(ws + 604800);
    float* s_box   = (float*)(ws + 638400);          // 16B-aligned (float4 loads)
    float* s_kps   = (float*)(ws + 772800);          // ends 1108800
    u64*   keep_words = (u64*)(ws + 1108800);        // 1056 B
    u64*   validw     = (u64*)(ws + 1110144);        // 1056 B
    u64*   rowflag    = (u64*)(ws + 1111296);        // 1056 B
    unsigned int* cnt = (unsigned int*)(ws + 1112448);   // 33600 B
    u64*   key        = (u64*)(ws + 1146368);            // 67200 B
    ulonglong2*   ent = (ulonglong2*)(ws + 1213568);     // 8400*32*16 = 4.3 MB
    u64*   diag       = (u64*)(ws + 5514368);            // 8448*8 B

    float* out = (float*)d_out;

    decode_kernel<<<(N_TOT + 255) / 256, 256, 0, stream>>>(
        score0, bbox0, kps0, score1, bbox1, kps1, score2, bbox2, kps2,
        logit, sig, box, kps, key, rank, cnt, validw, rowflag);
    rank_kernel<<<dim3(RT, RT), 256, 0, stream>>>(key, rank);
    scatter_kernel<<<33, 256, 0, stream>>>(rank, logit, sig, box, kps,
                                           s_logit, s_sig, s_box, s_kps, validw);
    pairs_kernel<<<dim3(MASK_WORDS, MASK_WORDS / 2 + 1), 64, 0, stream>>>(
        s_logit, s_box, cnt, ent, diag, rowflag);
    nms_kernel<<<1, 64, 0, stream>>>(rowflag, validw, cnt, diag, ent, keep_words);
    output_kernel<<<33, 256, 0, stream>>>(s_sig, s_box, s_kps, keep_words, out);
}